// Round 6
// baseline (10171.883 us; speedup 1.0000x reference)
//
#include <hip/hip_runtime.h>

// ============================================================================
// ENAS RNN scan + decode for MI355X (gfx950).  Round 9: persistent scan with
// staged (MLP-deep) loads, compiler-visible; no asm in the hot loop.
//
// Round-8 post-mortem: barrier fixed (scan 9950->6133us) but per-level cost
// still 16us: FETCH 5.7MB/level at only 357 GB/s effective = latency x MLP
// limit.  Cause: ldhl8's internal s_waitcnt vmcnt(0) capped each wave at 4
// outstanding loads.  Fix: two 4-unit stages per level body -- issue 16 A
// u64-atomic loads (sc0/sc1, compiler-tracked) + 8 B dwordx4 loads into
// register arrays, THEN compute.  ~24 outstanding/wave, safe spills, no
// pending-asm-register hazard.  Barrier/epilogue/math unchanged (round-8).
// Fallback to multi-launch if coop launch is rejected.
//
// MFMA 16x16x32 bf16 layouts (m89-verified):
//   A: lane holds A[m=lane&15][k=(lane>>4)*8 + j], j=0..7
//   B: lane holds B[k=(lane>>4)*8+j][n=lane&15]
//   C/D: col = lane&15, row = (lane>>4)*4 + reg
// ============================================================================

#define TPB 256            // helper kernels
#define STPB 1024          // scan blocks: 16 waves
#define GPB 189            // persistent grid (max level width = 3*NTILE)

#define Tt 64
#define Bb 64
#define Hh 1000
#define Ee 1000
#define Vv 10000
#define HP 1024                 // padded row stride for h buffers
#define SLOT (Bb * HP)          // elems per h slot
#define KW 2000                 // E + H (w_x* row length)
#define NTILE 63                // ceil(1000/16)

typedef unsigned short u16;
typedef unsigned long long u64;
typedef short bf16x8 __attribute__((ext_vector_type(8)));
typedef float f32x4 __attribute__((ext_vector_type(4)));

// ---- ws layout (bytes) ----
// hl (packed hi|lo u32): 12*SLOT*4 = 3,145,728 at ws+0
#define OFF_C0    3145728u     // c0 : 64*HP*4 = 262,144
#define OFF_OBF   3407872u     // obf: 4096*HP*2 (bf16 outputs for decode A)
                               // (first 32 KB double as barrier arr/rel during
                               //  scan; cvt_kernel overwrites them afterwards)
#define OFF_WC    11796480u
#define WC_WXH    0u           // bf16 w_xh  : 2e6*2 = 4,000,000
#define WC_WXC    4000000u     // bf16 w_xc  : 4,000,000
#define WC_WH     8000000u     // bf16 Wh    : 22,000,000
#define WC_WCC    30000000u    // bf16 Wc    : 22,000,000
#define WC_END    52000000u
#define WS_CACHED (OFF_WC + WC_END)   // 63,796,480

#define REL_OFF   (16384u / 4u)       // rel word, u32 index from arr base

// outb (fp32 leaf sums, 4096*1024*4 = 16,777,216 B) lives at the start of
// d_out (163.8 MB fp32 output); consumed by cvt before decode writes d_out.
#define OUTB_BYTES 16777216u

__device__ __forceinline__ float bf2f(u16 u) {
  union { unsigned int i; float f; } c; c.i = ((unsigned int)u) << 16; return c.f;
}
__device__ __forceinline__ u16 f2bf(float f) {
  union { float f; unsigned int i; } c; c.f = f;
  unsigned int u = c.i + 0x7FFFu + ((c.i >> 16) & 1u);
  return (u16)(u >> 16);
}
// Sanitize: clamp to +-16, maps NaN -> -16 (fmaxf/fminf return non-NaN arg).
__device__ __forceinline__ float sanf(float x) {
  return fminf(fmaxf(x, -16.0f), 16.0f);
}
__device__ __forceinline__ f32x4 mfma16(bf16x8 a, bf16x8 b, f32x4 c) {
  return __builtin_amdgcn_mfma_f32_16x16x32_bf16(a, b, c, 0, 0, 0);
}
__device__ __forceinline__ bf16x8 ld8(const u16* p) { return *(const bf16x8*)p; }
__device__ __forceinline__ bf16x8 cvt8(const float* p) {
  float4 v0 = *(const float4*)p, v1 = *(const float4*)(p + 4);
  bf16x8 r;
  r[0] = (short)f2bf(sanf(v0.x)); r[1] = (short)f2bf(sanf(v0.y));
  r[2] = (short)f2bf(sanf(v0.z)); r[3] = (short)f2bf(sanf(v0.w));
  r[4] = (short)f2bf(sanf(v1.x)); r[5] = (short)f2bf(sanf(v1.y));
  r[6] = (short)f2bf(sanf(v1.z)); r[7] = (short)f2bf(sanf(v1.w));
  return r;
}
// B-fragment load: cached bf16 (ws) or in-register f32->bf16. Element offset.
template<bool CB>
__device__ __forceinline__ bf16x8 ldB(const void* base, size_t off) {
  if constexpr (CB) return *(const bf16x8*)((const u16*)base + off);
  else              return cvt8((const float*)base + off);
}

// ---- coherent (LLC) access for mutable scan state ----
// A-fragment loads: 4x relaxed agent-scope u64 atomic loads (compile to
// global_load_dwordx2 sc0 sc1) -- compiler-tracked, pipeline-able, safe.
__device__ __forceinline__ void ldhl_issue(const unsigned* p, u64* w) {
  const u64* q = (const u64*)p;   // 8B-aligned: element offsets multiple of 8
  w[0] = __hip_atomic_load(q + 0, __ATOMIC_RELAXED, __HIP_MEMORY_SCOPE_AGENT);
  w[1] = __hip_atomic_load(q + 1, __ATOMIC_RELAXED, __HIP_MEMORY_SCOPE_AGENT);
  w[2] = __hip_atomic_load(q + 2, __ATOMIC_RELAXED, __HIP_MEMORY_SCOPE_AGENT);
  w[3] = __hip_atomic_load(q + 3, __ATOMIC_RELAXED, __HIP_MEMORY_SCOPE_AGENT);
}
__device__ __forceinline__ void unpk(const u64* w, bf16x8& hi, bf16x8& lo) {
  #pragma unroll
  for (int j = 0; j < 4; ++j) {
    unsigned e0 = (unsigned)w[j], e1 = (unsigned)(w[j] >> 32);
    hi[2 * j]     = (short)(u16)(e0 >> 16); lo[2 * j]     = (short)(u16)e0;
    hi[2 * j + 1] = (short)(u16)(e1 >> 16); lo[2 * j + 1] = (short)(u16)e1;
  }
}
__device__ __forceinline__ unsigned ldw(const unsigned* p) {
  return __hip_atomic_load((unsigned*)p, __ATOMIC_RELAXED, __HIP_MEMORY_SCOPE_AGENT);
}
__device__ __forceinline__ void stw(unsigned* p, unsigned v) {
  __hip_atomic_store(p, v, __ATOMIC_RELAXED, __HIP_MEMORY_SCOPE_AGENT);
}
__device__ __forceinline__ float ldf(const float* p) {
  return __hip_atomic_load((float*)p, __ATOMIC_RELAXED, __HIP_MEMORY_SCOPE_AGENT);
}
__device__ __forceinline__ void stf(float* p, float v) {
  __hip_atomic_store(p, v, __ATOMIC_RELAXED, __HIP_MEMORY_SCOPE_AGENT);
}

__device__ __forceinline__ float sigm(float x) { return 1.0f / (1.0f + __expf(-x)); }
__device__ __forceinline__ float tanh_(float x) {
  float e = __expf(-2.0f * fabsf(x));
  float t = (1.0f - e) / (1.0f + e);
  return x < 0.0f ? -t : t;
}
__device__ __forceinline__ float actf(int a, float x) {
  if (a == 0) return fmaxf(x, 0.0f);   // relu
  if (a == 1) return tanh_(x);         // tanh
  if (a == 2) return sigm(x);          // sigmoid
  return x;                            // identity
}

// Edge schedule, grouped by DAG level (positions 0..10).
// act: 0=relu 1=tanh 2=sigmoid 3=identity
__constant__ short g_e[11]    = {0, 1, 2, 3, 10, 4, 5, 6, 7, 8, 9};
__constant__ short g_src[11]  = {0, 0, 1, 1, 6, 2, 2, 3, 3, 4, 4};
__constant__ short g_dst[11]  = {1, 6, 2, 8, 7, 3, 9, 4, 10, 5, 11};
__constant__ short g_act[11]  = {0, 1, 0, 2, 1, 1, 0, 3, 1, 0, 2};
__constant__ short g_leaf[11] = {0, 0, 0, 1, 1, 0, 1, 0, 1, 1, 1};

// f32 -> sanitized bf16 (weight cache). n divisible by 4.
__global__ void __launch_bounds__(TPB) wcvt_kernel(const float* __restrict__ src,
                                                   u16* __restrict__ dst, int n) {
  int i = (blockIdx.x * TPB + threadIdx.x) * 4;
  if (i < n) {
    float4 v = *(const float4*)(src + i);
    dst[i + 0] = f2bf(sanf(v.x));
    dst[i + 1] = f2bf(sanf(v.y));
    dst[i + 2] = f2bf(sanf(v.z));
    dst[i + 3] = f2bf(sanf(v.w));
  }
}

// hidden [64,1000] f32 -> h slot 11 packed hi|lo (pads zeroed by memset).
__global__ void __launch_bounds__(TPB) stage_kernel(const float* __restrict__ hidden,
                                                    unsigned* __restrict__ hl) {
  int b = blockIdx.x;
  for (int k = threadIdx.x; k < Hh; k += TPB) {
    float x = sanf(hidden[b * Hh + k]);
    u16 h = f2bf(x);
    u16 l = f2bf(x - bf2f(h));
    hl[11 * SLOT + b * HP + k] = ((unsigned)h << 16) | l;
  }
}

// ---------------------------------------------------------------------------
// Contention-free grid barrier (round-8 proven).
// ---------------------------------------------------------------------------
__device__ __forceinline__ void gbar(unsigned* arr, unsigned ep) {
  asm volatile("s_waitcnt vmcnt(0) lgkmcnt(0)" ::: "memory");
  __syncthreads();
  const int tid = threadIdx.x;
  if (blockIdx.x == 0) {
    if (tid >= 1 && tid < GPB) {
      while (ldw(arr + tid * 16) < ep) __builtin_amdgcn_s_sleep(2);
    }
    __syncthreads();
    if (tid == 0) stw(arr + REL_OFF, ep);
  } else {
    if (tid == 0) {
      stw(arr + blockIdx.x * 16, ep);
      while (ldw(arr + REL_OFF) < ep) __builtin_amdgcn_s_sleep(2);
    }
    __syncthreads();
  }
  __builtin_amdgcn_sched_barrier(0);
  asm volatile("" ::: "memory");
}

// ---------------------------------------------------------------------------
// Per-level bodies.  1024 threads = 16 waves = kc (K-chunk, 4) x mquad (m, 4).
// Each wave owns 8 K-units; processed as two 4-unit stages: {issue 16 A +
// 8 B loads} -> {unpack + 16 MFMA}.  Split-K partials reduced through 32 KB
// LDS, epilogue by kc==0 waves.
// Uniform unit addressing: unit u has k=(cb+u)*32+koff; for kc==3, u==7 is
// the tail (B masked to quad==0; A overhang reads stay inside ws -- benign,
// multiplied by zero B).
// ---------------------------------------------------------------------------
template<bool CB>
__device__ __forceinline__ void lev0_body(
    const int bid, const int t,
    const int* __restrict__ inputs, const float* __restrict__ emb,
    const void* __restrict__ wxh, const float* __restrict__ bxh,
    const void* __restrict__ wxc, const float* __restrict__ bxc,
    unsigned* __restrict__ hl, float* __restrict__ c0b,
    float (*red)[8][64])
{
  const int tid = threadIdx.x;
  const int lane = tid & 63, wave = tid >> 6;
  const int mquad = wave & 3, kc = wave >> 2;
  const int l15 = lane & 15, quad = lane >> 4;
  const int koff = quad * 8;

  const int n0 = bid * 16;                      // 63 tiles
  const int nrow = n0 + l15;
  const int ncl = nrow < Hh ? nrow : Hh - 1;
  const size_t wrow = (size_t)ncl * KW;
  const int mrow = mquad * 16 + l15;
  int ix = inputs[t * Bb + mrow];
  ix = ix < 0 ? 0 : (ix >= Vv ? Vv - 1 : ix);   // defensive clamp
  const float* px = emb + (size_t)ix * Ee;
  const unsigned* ph = hl + 11 * SLOT + (size_t)mrow * HP;

  const int cb = kc * 8;

  f32x4 ac = {0.f, 0.f, 0.f, 0.f}, ah = {0.f, 0.f, 0.f, 0.f};

  // phase 1: x part (k 0..999), A = emb converted f32->bf16 (normal cached
  // loads, compiler-pipelined).  Unit 7 of kc==3 is the tail: A masked to
  // quad==0 (embedding row end); B row len 2000 -> always in-bounds.
  #pragma unroll 2
  for (int u = 0; u < 8; ++u) {
    int k = (cb + u) * 32 + koff;
    bf16x8 a;
    if (kc == 3 && u == 7) {
      bf16x8 z = {0, 0, 0, 0, 0, 0, 0, 0};
      a = z;
      if (quad == 0) a = cvt8(px + k);
    } else {
      a = cvt8(px + k);
    }
    ac = mfma16(a, ldB<CB>(wxc, wrow + k), ac);
    ah = mfma16(a, ldB<CB>(wxh, wrow + k), ah);
  }

  // phase 2: h_prev part (hi + lo from packed u32), B cols 1000..1999.
  // Two 4-unit stages; A via staged u64 atomic loads for deep MLP.
  #pragma unroll
  for (int h2 = 0; h2 < 2; ++h2) {
    u64 aw[4][4];
    bf16x8 wb0[4], wb1[4];
    #pragma unroll
    for (int u = 0; u < 4; ++u) {
      const int uu = h2 * 4 + u;
      const int k = (cb + uu) * 32 + koff;
      ldhl_issue(ph + k, aw[u]);
      if (kc == 3 && uu == 7) {   // tail: mask B (w_x* row end)
        bf16x8 z = {0, 0, 0, 0, 0, 0, 0, 0};
        wb0[u] = z; wb1[u] = z;
        if (quad == 0) { wb0[u] = ldB<CB>(wxc, wrow + 1000 + k);
                         wb1[u] = ldB<CB>(wxh, wrow + 1000 + k); }
      } else {
        wb0[u] = ldB<CB>(wxc, wrow + 1000 + k);
        wb1[u] = ldB<CB>(wxh, wrow + 1000 + k);
      }
    }
    #pragma unroll
    for (int u = 0; u < 4; ++u) {
      bf16x8 a0, a1; unpk(aw[u], a0, a1);
      ac = mfma16(a0, wb0[u], ac); ac = mfma16(a1, wb0[u], ac);
      ah = mfma16(a0, wb1[u], ah); ah = mfma16(a1, wb1[u], ah);
    }
  }

  // split-K reduction through LDS
  #pragma unroll
  for (int r = 0; r < 4; ++r) {
    red[wave][r][lane]     = ac[r];
    red[wave][4 + r][lane] = ah[r];
  }
  __syncthreads();
  if (kc == 0) {
    #pragma unroll
    for (int p = 1; p < 4; ++p) {
      const int w2 = p * 4 + mquad;
      #pragma unroll
      for (int r = 0; r < 4; ++r) {
        ac[r] += red[w2][r][lane];
        ah[r] += red[w2][4 + r][lane];
      }
    }
    const int ne = n0 + l15;
    if (ne < Hh) {
      float bxcv = sanf(bxc[ne]), bxhv = sanf(bxh[ne]);
      #pragma unroll
      for (int r = 0; r < 4; ++r) {
        int me = mquad * 16 + quad * 4 + r;
        size_t idx = (size_t)me * HP + ne;
        float c0v = sigm(ac[r] + bxcv);
        unsigned wprev = ldw(hl + 11 * SLOT + idx);
        float hp = bf2f((u16)(wprev >> 16)) + bf2f((u16)(wprev & 0xFFFFu));
        float h0 = sanf(c0v * tanh_(ah[r] + bxhv) + (1.0f - c0v) * hp);
        stf(c0b + idx, c0v);
        u16 hb = f2bf(h0);
        u16 lb = f2bf(h0 - bf2f(hb));
        stw(hl + idx, ((unsigned)hb << 16) | lb);   // slot 0
      }
    }
  }
}

template<bool CB>
__device__ __forceinline__ void edge_body(
    const int bid, const int e0, const int t,
    const void* __restrict__ Wh, const void* __restrict__ Wc,
    unsigned* __restrict__ hl, const float* __restrict__ c0b,
    float* __restrict__ outb, float (*red)[8][64])
{
  const int tid = threadIdx.x;
  const int lane = tid & 63, wave = tid >> 6;
  const int mquad = wave & 3, kc = wave >> 2;
  const int l15 = lane & 15, quad = lane >> 4;
  const int koff = quad * 8;

  const int er = bid / NTILE;
  const int e = e0 + er;
  const int n0 = (bid - er * NTILE) * 16;
  const int we = g_e[e], src = g_src[e], dst = g_dst[e];
  const int nrow = n0 + l15;
  const int ncl = nrow < Hh ? nrow : Hh - 1;
  const size_t wrow = (size_t)we * (Hh * Hh) + (size_t)ncl * Hh;
  const int mrow = mquad * 16 + l15;
  const unsigned* pa = hl + (size_t)src * SLOT + (size_t)mrow * HP;

  const int cb = kc * 8;

  f32x4 ac = {0.f, 0.f, 0.f, 0.f}, ah = {0.f, 0.f, 0.f, 0.f};
  #pragma unroll
  for (int h2 = 0; h2 < 2; ++h2) {
    u64 aw[4][4];
    bf16x8 wb0[4], wb1[4];
    #pragma unroll
    for (int u = 0; u < 4; ++u) {
      const int uu = h2 * 4 + u;
      const int k = (cb + uu) * 32 + koff;
      ldhl_issue(pa + k, aw[u]);
      if (kc == 3 && uu == 7) {   // tail: mask B (weight row end)
        bf16x8 z = {0, 0, 0, 0, 0, 0, 0, 0};
        wb0[u] = z; wb1[u] = z;
        if (quad == 0) { wb0[u] = ldB<CB>(Wc, wrow + k);
                         wb1[u] = ldB<CB>(Wh, wrow + k); }
      } else {
        wb0[u] = ldB<CB>(Wc, wrow + k);
        wb1[u] = ldB<CB>(Wh, wrow + k);
      }
    }
    #pragma unroll
    for (int u = 0; u < 4; ++u) {
      bf16x8 a0, a1; unpk(aw[u], a0, a1);
      ac = mfma16(a0, wb0[u], ac); ac = mfma16(a1, wb0[u], ac);
      ah = mfma16(a0, wb1[u], ah); ah = mfma16(a1, wb1[u], ah);
    }
  }

  // split-K reduction through LDS
  #pragma unroll
  for (int r = 0; r < 4; ++r) {
    red[wave][r][lane]     = ac[r];
    red[wave][4 + r][lane] = ah[r];
  }
  __syncthreads();
  if (kc == 0) {
    #pragma unroll
    for (int p = 1; p < 4; ++p) {
      const int w2 = p * 4 + mquad;
      #pragma unroll
      for (int r = 0; r < 4; ++r) {
        ac[r] += red[w2][r][lane];
        ah[r] += red[w2][4 + r][lane];
      }
    }
    const int ne = n0 + l15;
    if (ne < Hh) {
      const int act = g_act[e], leaf = g_leaf[e];
      const unsigned* pi = hl + (size_t)src * SLOT;
      unsigned* pj = hl + (size_t)dst * SLOT;
      #pragma unroll
      for (int r = 0; r < 4; ++r) {
        int me = mquad * 16 + quad * 4 + r;
        size_t idx = (size_t)me * HP + ne;
        float cj = sigm(ac[r]);
        float av = actf(act, ah[r]);
        unsigned wi = ldw(pi + idx);
        float hi_v = bf2f((u16)(wi >> 16)) + bf2f((u16)(wi & 0xFFFFu));
        float hj = sanf(cj * av + (1.0f - ldf(c0b + idx)) * hi_v);  // blend uses c0 (!)
        u16 hb = f2bf(hj);
        u16 lb = f2bf(hj - bf2f(hb));
        stw(pj + idx, ((unsigned)hb << 16) | lb);
        if (leaf) atomicAdd(outb + (size_t)(t * Bb + me) * HP + ne, hj);
      }
    }
  }
}

// ---------------------------------------------------------------------------
// Persistent scan: all 64 timesteps, 6 gbar-separated phases each.
// ---------------------------------------------------------------------------
template<bool CB>
__global__ void __launch_bounds__(STPB) scan_kernel(
    const int* __restrict__ inputs, const float* __restrict__ emb,
    const void* __restrict__ wxh, const float* __restrict__ bxh,
    const void* __restrict__ wxc, const float* __restrict__ bxc,
    const void* __restrict__ Wh, const void* __restrict__ Wc,
    unsigned* __restrict__ hl, float* __restrict__ c0b,
    float* __restrict__ outb, unsigned* __restrict__ arr)
{
  __shared__ float red[16][8][64];      // 32 KB
  const int bid = blockIdx.x;
  unsigned ep = 0;

  for (int t = 0; t < Tt; ++t) {
    if (bid < NTILE)
      lev0_body<CB>(bid, t, inputs, emb, wxh, bxh, wxc, bxc, hl, c0b, red);
    gbar(arr, ++ep);
    if (bid < 2 * NTILE) edge_body<CB>(bid, 0, t, Wh, Wc, hl, c0b, outb, red);
    gbar(arr, ++ep);
    if (bid < 3 * NTILE) edge_body<CB>(bid, 2, t, Wh, Wc, hl, c0b, outb, red);
    gbar(arr, ++ep);
    if (bid < 2 * NTILE) edge_body<CB>(bid, 5, t, Wh, Wc, hl, c0b, outb, red);
    gbar(arr, ++ep);
    if (bid < 2 * NTILE) edge_body<CB>(bid, 7, t, Wh, Wc, hl, c0b, outb, red);
    gbar(arr, ++ep);
    if (bid < 2 * NTILE) edge_body<CB>(bid, 9, t, Wh, Wc, hl, c0b, outb, red);
    gbar(arr, ++ep);
  }
}

// ---------------------------------------------------------------------------
// Fallback multi-launch kernels (kernel boundary = sync).
// ---------------------------------------------------------------------------
template<bool CB>
__global__ void __launch_bounds__(STPB) lev0_kernel(
    int t, const int* __restrict__ inputs, const float* __restrict__ emb,
    const void* __restrict__ wxh, const float* __restrict__ bxh,
    const void* __restrict__ wxc, const float* __restrict__ bxc,
    unsigned* __restrict__ hl, float* __restrict__ c0b)
{
  __shared__ float red[16][8][64];
  lev0_body<CB>(blockIdx.x, t, inputs, emb, wxh, bxh, wxc, bxc, hl, c0b, red);
}

template<bool CB>
__global__ void __launch_bounds__(STPB) edge_kernel(
    int e0, int t, const void* __restrict__ Wh, const void* __restrict__ Wc,
    unsigned* __restrict__ hl, const float* __restrict__ c0b,
    float* __restrict__ outb)
{
  __shared__ float red[16][8][64];
  edge_body<CB>(blockIdx.x, e0, t, Wh, Wc, hl, c0b, outb, red);
}

// fp32 leaf sums (in d_out) -> bf16 * (1/6) into ws.obf; pads stay zero.
__global__ void __launch_bounds__(TPB) cvt_kernel(const float* __restrict__ outb,
                                                  u16* __restrict__ obf) {
  size_t i = ((size_t)blockIdx.x * TPB + threadIdx.x) * 4;
  float4 v = *(const float4*)(outb + i);
  const float s = 1.0f / 6.0f;
  obf[i + 0] = f2bf(sanf(v.x * s));
  obf[i + 1] = f2bf(sanf(v.y * s));
  obf[i + 2] = f2bf(sanf(v.z * s));
  obf[i + 3] = f2bf(sanf(v.w * s));
}

// decoded[4096,10000] = out @ dec_w.T + dec_b, f32 out. 64x64 tile per WG.
__global__ void __launch_bounds__(TPB) decode_kernel(
    const u16* __restrict__ obf, const float* __restrict__ decw,
    const float* __restrict__ decb, float* __restrict__ out)
{
  const int tid = threadIdx.x;
  const int lane = tid & 63, wave = tid >> 6;
  const int l15 = lane & 15, quad = lane >> 4;
  const int bm = blockIdx.x % 64;   // consecutive blocks share bn -> B reuse in L2
  const int bn = blockIdx.x / 64;
  const int mrow = bm * 64 + wave * 16 + l15;
  const u16* pa = obf + (size_t)mrow * HP;
  const float* pb[4];
  #pragma unroll
  for (int j = 0; j < 4; ++j) {
    int v = bn * 64 + j * 16 + l15;
    if (v > Vv - 1) v = Vv - 1;
    pb[j] = decw + (size_t)v * Hh;
  }
  f32x4 acc[4];
  #pragma unroll
  for (int j = 0; j < 4; ++j) acc[j] = (f32x4){0.f, 0.f, 0.f, 0.f};
  const int koff = quad * 8;
  #pragma unroll 2
  for (int c = 0; c < 31; ++c) {
    int k = c * 32 + koff;
    bf16x8 a = ld8(pa + k);
    #pragma unroll
    for (int j = 0; j < 4; ++j) acc[j] = mfma16(a, cvt8(pb[j] + k), acc[j]);
  }
  { // tail: A covers zeroed pads (in-bounds); mask B (dec_w row end)
    int k = 992 + koff;
    bf16x8 a = ld8(pa + k);
    bf16x8 z = {0, 0, 0, 0, 0, 0, 0, 0};
    #pragma unroll
    for (int j = 0; j < 4; ++j) {
      bf16x8 b = z;
      if (quad == 0) b = cvt8(pb[j] + k);
      acc[j] = mfma16(a, b, acc[j]);
    }
  }
  #pragma unroll
  for (int j = 0; j < 4; ++j) {
    int ne = bn * 64 + j * 16 + l15;
    if (ne < Vv) {
      float bv = sanf(decb[ne]);
      #pragma unroll
      for (int r = 0; r < 4; ++r) {
        int me = bm * 64 + wave * 16 + quad * 4 + r;
        out[(size_t)me * Vv + ne] = acc[j][r] + bv;
      }
    }
  }
}

extern "C" void kernel_launch(void* const* d_in, const int* in_sizes, int n_in,
                              void* d_out, int out_size, void* d_ws, size_t ws_size,
                              hipStream_t stream) {
  const int*   inputs = (const int*)d_in[0];
  const float* hidden = (const float*)d_in[1];
  const float* emb    = (const float*)d_in[2];
  const float* wxh    = (const float*)d_in[3];
  const float* bxh    = (const float*)d_in[4];
  const float* wxc    = (const float*)d_in[5];
  const float* bxc    = (const float*)d_in[6];
  const float* Wh     = (const float*)d_in[7];
  const float* Wc     = (const float*)d_in[8];
  const float* decw   = (const float*)d_in[9];
  const float* decb   = (const float*)d_in[10];

  char* ws = (char*)d_ws;
  unsigned* hl  = (unsigned*)(ws);
  float*    c0b = (float*)(ws + OFF_C0);
  u16*      obf = (u16*)(ws + OFF_OBF);
  unsigned* arr = (unsigned*)(ws + OFF_OBF);  // barrier region, overwritten by cvt
  float*    outb = (float*)d_out;   // fp32 leaf sums, consumed before decode

  const bool cached = (ws_size >= (size_t)WS_CACHED);
  u16* wxhb = (u16*)(ws + OFF_WC + WC_WXH);
  u16* wxcb = (u16*)(ws + OFF_WC + WC_WXC);
  u16* Whb  = (u16*)(ws + OFF_WC + WC_WH);
  u16* Wcb  = (u16*)(ws + OFF_WC + WC_WCC);

  // zero hl (pads must be 0) + c0 + barrier arr/rel, and leaf-sum region
  hipMemsetAsync(ws, 0, OFF_OBF, stream);
  hipMemsetAsync(ws + OFF_OBF, 0, 32768, stream);
  hipMemsetAsync(d_out, 0, OUTB_BYTES, stream);

  if (cached) {
    wcvt_kernel<<<(2000000 / 4 + TPB - 1) / TPB, TPB, 0, stream>>>(wxh, wxhb, 2000000);
    wcvt_kernel<<<(2000000 / 4 + TPB - 1) / TPB, TPB, 0, stream>>>(wxc, wxcb, 2000000);
    wcvt_kernel<<<(11000000 / 4 + TPB - 1) / TPB, TPB, 0, stream>>>(Wh, Whb, 11000000);
    wcvt_kernel<<<(11000000 / 4 + TPB - 1) / TPB, TPB, 0, stream>>>(Wc, Wcb, 11000000);
  }
  stage_kernel<<<Bb, TPB, 0, stream>>>(hidden, hl);

  const void* a_wxh = cached ? (const void*)wxhb : (const void*)wxh;
  const void* a_wxc = cached ? (const void*)wxcb : (const void*)wxc;
  const void* a_Wh  = cached ? (const void*)Whb  : (const void*)Wh;
  const void* a_Wc  = cached ? (const void*)Wcb  : (const void*)Wc;
  void* ka[12] = {(void*)&inputs, (void*)&emb, (void*)&a_wxh, (void*)&bxh,
                  (void*)&a_wxc, (void*)&bxc, (void*)&a_Wh, (void*)&a_Wc,
                  (void*)&hl, (void*)&c0b, (void*)&outb, (void*)&arr};
  dim3 sgrid(GPB), sblk(STPB);
  hipError_t ce = cached
    ? hipLaunchCooperativeKernel(scan_kernel<true>,  sgrid, sblk, ka, 0, stream)
    : hipLaunchCooperativeKernel(scan_kernel<false>, sgrid, sblk, ka, 0, stream);

  if (ce != hipSuccess) {
    (void)hipGetLastError();   // clear sticky error; fall back to multi-launch
    static const int lev_off[5] = {0, 2, 5, 7, 9};
    static const int lev_cnt[5] = {2, 3, 2, 2, 2};
    for (int t = 0; t < Tt; ++t) {
      if (cached) {
        lev0_kernel<true><<<NTILE, STPB, 0, stream>>>(t, inputs, emb, wxhb, bxh,
                                                      wxcb, bxc, hl, c0b);
        for (int lev = 0; lev < 5; ++lev)
          edge_kernel<true><<<lev_cnt[lev] * NTILE, STPB, 0, stream>>>(
              lev_off[lev], t, Whb, Wcb, hl, c0b, outb);
      } else {
        lev0_kernel<false><<<NTILE, STPB, 0, stream>>>(t, inputs, emb, wxh, bxh,
                                                       wxc, bxc, hl, c0b);
        for (int lev = 0; lev < 5; ++lev)
          edge_kernel<false><<<lev_cnt[lev] * NTILE, STPB, 0, stream>>>(
              lev_off[lev], t, Wh, Wc, hl, c0b, outb);
      }
    }
  }

  cvt_kernel<<<(Tt * Bb * HP) / (TPB * 4), TPB, 0, stream>>>(outb, obf);
  decode_kernel<<<64 * 157, TPB, 0, stream>>>(obf, decw, decb, (float*)d_out);
}

// Round 7
// 10114.288 us; speedup vs baseline: 1.0057x; 1.0057x over previous
//
#include <hip/hip_runtime.h>

// ============================================================================
// ENAS RNN scan + decode for MI355X (gfx950).  Round 10: round-9 staged loads
// with the VGPR budget actually available (launch_bounds min-waves fix).
//
// Round-9 post-mortem: staging arrays spilled to scratch -- VGPR_Count stayed
// 64 because __launch_bounds__(1024) w/o min-waves targets 2 blocks/CU
// (8 waves/EU -> 64-VGPR cap); grid is 189 <= 256 CUs so that co-residency
// is worthless.  FETCH grew 2.19->2.43 GB (scratch) and scan regressed.
// Fix: __launch_bounds__(1024, 4) = 1 block/CU = 128-VGPR cap; staging
// arrays (16 u64 A-loads + 8 dwordx4 B-loads in flight) fit in registers.
// Barrier/epilogue/math byte-identical to round 9.
// Fallback to multi-launch if coop launch is rejected.
//
// MFMA 16x16x32 bf16 layouts (m89-verified):
//   A: lane holds A[m=lane&15][k=(lane>>4)*8 + j], j=0..7
//   B: lane holds B[k=(lane>>4)*8+j][n=lane&15]
//   C/D: col = lane&15, row = (lane>>4)*4 + reg
// ============================================================================

#define TPB 256            // helper kernels
#define STPB 1024          // scan blocks: 16 waves
#define SMIN 4             // min waves/EU: 1 block/CU -> 128-VGPR cap
#define GPB 189            // persistent grid (max level width = 3*NTILE)

#define Tt 64
#define Bb 64
#define Hh 1000
#define Ee 1000
#define Vv 10000
#define HP 1024                 // padded row stride for h buffers
#define SLOT (Bb * HP)          // elems per h slot
#define KW 2000                 // E + H (w_x* row length)
#define NTILE 63                // ceil(1000/16)

typedef unsigned short u16;
typedef unsigned long long u64;
typedef short bf16x8 __attribute__((ext_vector_type(8)));
typedef float f32x4 __attribute__((ext_vector_type(4)));

// ---- ws layout (bytes) ----
// hl (packed hi|lo u32): 12*SLOT*4 = 3,145,728 at ws+0
#define OFF_C0    3145728u     // c0 : 64*HP*4 = 262,144
#define OFF_OBF   3407872u     // obf: 4096*HP*2 (bf16 outputs for decode A)
                               // (first 32 KB double as barrier arr/rel during
                               //  scan; cvt_kernel overwrites them afterwards)
#define OFF_WC    11796480u
#define WC_WXH    0u           // bf16 w_xh  : 2e6*2 = 4,000,000
#define WC_WXC    4000000u     // bf16 w_xc  : 4,000,000
#define WC_WH     8000000u     // bf16 Wh    : 22,000,000
#define WC_WCC    30000000u    // bf16 Wc    : 22,000,000
#define WC_END    52000000u
#define WS_CACHED (OFF_WC + WC_END)   // 63,796,480

#define REL_OFF   (16384u / 4u)       // rel word, u32 index from arr base

// outb (fp32 leaf sums, 4096*1024*4 = 16,777,216 B) lives at the start of
// d_out (163.8 MB fp32 output); consumed by cvt before decode writes d_out.
#define OUTB_BYTES 16777216u

__device__ __forceinline__ float bf2f(u16 u) {
  union { unsigned int i; float f; } c; c.i = ((unsigned int)u) << 16; return c.f;
}
__device__ __forceinline__ u16 f2bf(float f) {
  union { float f; unsigned int i; } c; c.f = f;
  unsigned int u = c.i + 0x7FFFu + ((c.i >> 16) & 1u);
  return (u16)(u >> 16);
}
// Sanitize: clamp to +-16, maps NaN -> -16 (fmaxf/fminf return non-NaN arg).
__device__ __forceinline__ float sanf(float x) {
  return fminf(fmaxf(x, -16.0f), 16.0f);
}
__device__ __forceinline__ f32x4 mfma16(bf16x8 a, bf16x8 b, f32x4 c) {
  return __builtin_amdgcn_mfma_f32_16x16x32_bf16(a, b, c, 0, 0, 0);
}
__device__ __forceinline__ bf16x8 ld8(const u16* p) { return *(const bf16x8*)p; }
__device__ __forceinline__ bf16x8 cvt8(const float* p) {
  float4 v0 = *(const float4*)p, v1 = *(const float4*)(p + 4);
  bf16x8 r;
  r[0] = (short)f2bf(sanf(v0.x)); r[1] = (short)f2bf(sanf(v0.y));
  r[2] = (short)f2bf(sanf(v0.z)); r[3] = (short)f2bf(sanf(v0.w));
  r[4] = (short)f2bf(sanf(v1.x)); r[5] = (short)f2bf(sanf(v1.y));
  r[6] = (short)f2bf(sanf(v1.z)); r[7] = (short)f2bf(sanf(v1.w));
  return r;
}
// B-fragment load: cached bf16 (ws) or in-register f32->bf16. Element offset.
template<bool CB>
__device__ __forceinline__ bf16x8 ldB(const void* base, size_t off) {
  if constexpr (CB) return *(const bf16x8*)((const u16*)base + off);
  else              return cvt8((const float*)base + off);
}

// ---- coherent (LLC) access for mutable scan state ----
// A-fragment loads: 4x relaxed agent-scope u64 atomic loads (compile to
// global_load_dwordx2 sc0 sc1) -- compiler-tracked, pipeline-able, safe.
__device__ __forceinline__ void ldhl_issue(const unsigned* p, u64* w) {
  const u64* q = (const u64*)p;   // 8B-aligned: element offsets multiple of 8
  w[0] = __hip_atomic_load(q + 0, __ATOMIC_RELAXED, __HIP_MEMORY_SCOPE_AGENT);
  w[1] = __hip_atomic_load(q + 1, __ATOMIC_RELAXED, __HIP_MEMORY_SCOPE_AGENT);
  w[2] = __hip_atomic_load(q + 2, __ATOMIC_RELAXED, __HIP_MEMORY_SCOPE_AGENT);
  w[3] = __hip_atomic_load(q + 3, __ATOMIC_RELAXED, __HIP_MEMORY_SCOPE_AGENT);
}
__device__ __forceinline__ void unpk(const u64* w, bf16x8& hi, bf16x8& lo) {
  #pragma unroll
  for (int j = 0; j < 4; ++j) {
    unsigned e0 = (unsigned)w[j], e1 = (unsigned)(w[j] >> 32);
    hi[2 * j]     = (short)(u16)(e0 >> 16); lo[2 * j]     = (short)(u16)e0;
    hi[2 * j + 1] = (short)(u16)(e1 >> 16); lo[2 * j + 1] = (short)(u16)e1;
  }
}
__device__ __forceinline__ unsigned ldw(const unsigned* p) {
  return __hip_atomic_load((unsigned*)p, __ATOMIC_RELAXED, __HIP_MEMORY_SCOPE_AGENT);
}
__device__ __forceinline__ void stw(unsigned* p, unsigned v) {
  __hip_atomic_store(p, v, __ATOMIC_RELAXED, __HIP_MEMORY_SCOPE_AGENT);
}
__device__ __forceinline__ float ldf(const float* p) {
  return __hip_atomic_load((float*)p, __ATOMIC_RELAXED, __HIP_MEMORY_SCOPE_AGENT);
}
__device__ __forceinline__ void stf(float* p, float v) {
  __hip_atomic_store(p, v, __ATOMIC_RELAXED, __HIP_MEMORY_SCOPE_AGENT);
}

__device__ __forceinline__ float sigm(float x) { return 1.0f / (1.0f + __expf(-x)); }
__device__ __forceinline__ float tanh_(float x) {
  float e = __expf(-2.0f * fabsf(x));
  float t = (1.0f - e) / (1.0f + e);
  return x < 0.0f ? -t : t;
}
__device__ __forceinline__ float actf(int a, float x) {
  if (a == 0) return fmaxf(x, 0.0f);   // relu
  if (a == 1) return tanh_(x);         // tanh
  if (a == 2) return sigm(x);          // sigmoid
  return x;                            // identity
}

// Edge schedule, grouped by DAG level (positions 0..10).
// act: 0=relu 1=tanh 2=sigmoid 3=identity
__constant__ short g_e[11]    = {0, 1, 2, 3, 10, 4, 5, 6, 7, 8, 9};
__constant__ short g_src[11]  = {0, 0, 1, 1, 6, 2, 2, 3, 3, 4, 4};
__constant__ short g_dst[11]  = {1, 6, 2, 8, 7, 3, 9, 4, 10, 5, 11};
__constant__ short g_act[11]  = {0, 1, 0, 2, 1, 1, 0, 3, 1, 0, 2};
__constant__ short g_leaf[11] = {0, 0, 0, 1, 1, 0, 1, 0, 1, 1, 1};

// f32 -> sanitized bf16 (weight cache). n divisible by 4.
__global__ void __launch_bounds__(TPB) wcvt_kernel(const float* __restrict__ src,
                                                   u16* __restrict__ dst, int n) {
  int i = (blockIdx.x * TPB + threadIdx.x) * 4;
  if (i < n) {
    float4 v = *(const float4*)(src + i);
    dst[i + 0] = f2bf(sanf(v.x));
    dst[i + 1] = f2bf(sanf(v.y));
    dst[i + 2] = f2bf(sanf(v.z));
    dst[i + 3] = f2bf(sanf(v.w));
  }
}

// hidden [64,1000] f32 -> h slot 11 packed hi|lo (pads zeroed by memset).
__global__ void __launch_bounds__(TPB) stage_kernel(const float* __restrict__ hidden,
                                                    unsigned* __restrict__ hl) {
  int b = blockIdx.x;
  for (int k = threadIdx.x; k < Hh; k += TPB) {
    float x = sanf(hidden[b * Hh + k]);
    u16 h = f2bf(x);
    u16 l = f2bf(x - bf2f(h));
    hl[11 * SLOT + b * HP + k] = ((unsigned)h << 16) | l;
  }
}

// ---------------------------------------------------------------------------
// Contention-free grid barrier (round-8 proven).
// ---------------------------------------------------------------------------
__device__ __forceinline__ void gbar(unsigned* arr, unsigned ep) {
  asm volatile("s_waitcnt vmcnt(0) lgkmcnt(0)" ::: "memory");
  __syncthreads();
  const int tid = threadIdx.x;
  if (blockIdx.x == 0) {
    if (tid >= 1 && tid < GPB) {
      while (ldw(arr + tid * 16) < ep) __builtin_amdgcn_s_sleep(2);
    }
    __syncthreads();
    if (tid == 0) stw(arr + REL_OFF, ep);
  } else {
    if (tid == 0) {
      stw(arr + blockIdx.x * 16, ep);
      while (ldw(arr + REL_OFF) < ep) __builtin_amdgcn_s_sleep(2);
    }
    __syncthreads();
  }
  __builtin_amdgcn_sched_barrier(0);
  asm volatile("" ::: "memory");
}

// ---------------------------------------------------------------------------
// Per-level bodies.  1024 threads = 16 waves = kc (K-chunk, 4) x mquad (m, 4).
// Each wave owns 8 K-units; processed as two 4-unit stages: {issue 16 A +
// 8 B loads into register arrays} -> {unpack + 16 MFMA}.  Split-K partials
// reduced through 32 KB LDS, epilogue by kc==0 waves.
// ---------------------------------------------------------------------------
template<bool CB>
__device__ __forceinline__ void lev0_body(
    const int bid, const int t,
    const int* __restrict__ inputs, const float* __restrict__ emb,
    const void* __restrict__ wxh, const float* __restrict__ bxh,
    const void* __restrict__ wxc, const float* __restrict__ bxc,
    unsigned* __restrict__ hl, float* __restrict__ c0b,
    float (*red)[8][64])
{
  const int tid = threadIdx.x;
  const int lane = tid & 63, wave = tid >> 6;
  const int mquad = wave & 3, kc = wave >> 2;
  const int l15 = lane & 15, quad = lane >> 4;
  const int koff = quad * 8;

  const int n0 = bid * 16;                      // 63 tiles
  const int nrow = n0 + l15;
  const int ncl = nrow < Hh ? nrow : Hh - 1;
  const size_t wrow = (size_t)ncl * KW;
  const int mrow = mquad * 16 + l15;
  int ix = inputs[t * Bb + mrow];
  ix = ix < 0 ? 0 : (ix >= Vv ? Vv - 1 : ix);   // defensive clamp
  const float* px = emb + (size_t)ix * Ee;
  const unsigned* ph = hl + 11 * SLOT + (size_t)mrow * HP;

  const int cb = kc * 8;

  f32x4 ac = {0.f, 0.f, 0.f, 0.f}, ah = {0.f, 0.f, 0.f, 0.f};

  // phase 1: x part (k 0..999), A = emb converted f32->bf16 (normal cached
  // loads, compiler-pipelined).  Unit 7 of kc==3 is the tail: A masked to
  // quad==0 (embedding row end); B row len 2000 -> always in-bounds.
  #pragma unroll 2
  for (int u = 0; u < 8; ++u) {
    int k = (cb + u) * 32 + koff;
    bf16x8 a;
    if (kc == 3 && u == 7) {
      bf16x8 z = {0, 0, 0, 0, 0, 0, 0, 0};
      a = z;
      if (quad == 0) a = cvt8(px + k);
    } else {
      a = cvt8(px + k);
    }
    ac = mfma16(a, ldB<CB>(wxc, wrow + k), ac);
    ah = mfma16(a, ldB<CB>(wxh, wrow + k), ah);
  }

  // phase 2: h_prev part (hi + lo from packed u32), B cols 1000..1999.
  // Two 4-unit stages; A via staged u64 atomic loads for deep MLP.
  #pragma unroll
  for (int h2 = 0; h2 < 2; ++h2) {
    u64 aw[4][4];
    bf16x8 wb0[4], wb1[4];
    #pragma unroll
    for (int u = 0; u < 4; ++u) {
      const int uu = h2 * 4 + u;
      const int k = (cb + uu) * 32 + koff;
      ldhl_issue(ph + k, aw[u]);
      if (kc == 3 && uu == 7) {   // tail: mask B (w_x* row end)
        bf16x8 z = {0, 0, 0, 0, 0, 0, 0, 0};
        wb0[u] = z; wb1[u] = z;
        if (quad == 0) { wb0[u] = ldB<CB>(wxc, wrow + 1000 + k);
                         wb1[u] = ldB<CB>(wxh, wrow + 1000 + k); }
      } else {
        wb0[u] = ldB<CB>(wxc, wrow + 1000 + k);
        wb1[u] = ldB<CB>(wxh, wrow + 1000 + k);
      }
    }
    #pragma unroll
    for (int u = 0; u < 4; ++u) {
      bf16x8 a0, a1; unpk(aw[u], a0, a1);
      ac = mfma16(a0, wb0[u], ac); ac = mfma16(a1, wb0[u], ac);
      ah = mfma16(a0, wb1[u], ah); ah = mfma16(a1, wb1[u], ah);
    }
  }

  // split-K reduction through LDS
  #pragma unroll
  for (int r = 0; r < 4; ++r) {
    red[wave][r][lane]     = ac[r];
    red[wave][4 + r][lane] = ah[r];
  }
  __syncthreads();
  if (kc == 0) {
    #pragma unroll
    for (int p = 1; p < 4; ++p) {
      const int w2 = p * 4 + mquad;
      #pragma unroll
      for (int r = 0; r < 4; ++r) {
        ac[r] += red[w2][r][lane];
        ah[r] += red[w2][4 + r][lane];
      }
    }
    const int ne = n0 + l15;
    if (ne < Hh) {
      float bxcv = sanf(bxc[ne]), bxhv = sanf(bxh[ne]);
      #pragma unroll
      for (int r = 0; r < 4; ++r) {
        int me = mquad * 16 + quad * 4 + r;
        size_t idx = (size_t)me * HP + ne;
        float c0v = sigm(ac[r] + bxcv);
        unsigned wprev = ldw(hl + 11 * SLOT + idx);
        float hp = bf2f((u16)(wprev >> 16)) + bf2f((u16)(wprev & 0xFFFFu));
        float h0 = sanf(c0v * tanh_(ah[r] + bxhv) + (1.0f - c0v) * hp);
        stf(c0b + idx, c0v);
        u16 hb = f2bf(h0);
        u16 lb = f2bf(h0 - bf2f(hb));
        stw(hl + idx, ((unsigned)hb << 16) | lb);   // slot 0
      }
    }
  }
}

template<bool CB>
__device__ __forceinline__ void edge_body(
    const int bid, const int e0, const int t,
    const void* __restrict__ Wh, const void* __restrict__ Wc,
    unsigned* __restrict__ hl, const float* __restrict__ c0b,
    float* __restrict__ outb, float (*red)[8][64])
{
  const int tid = threadIdx.x;
  const int lane = tid & 63, wave = tid >> 6;
  const int mquad = wave & 3, kc = wave >> 2;
  const int l15 = lane & 15, quad = lane >> 4;
  const int koff = quad * 8;

  const int er = bid / NTILE;
  const int e = e0 + er;
  const int n0 = (bid - er * NTILE) * 16;
  const int we = g_e[e], src = g_src[e], dst = g_dst[e];
  const int nrow = n0 + l15;
  const int ncl = nrow < Hh ? nrow : Hh - 1;
  const size_t wrow = (size_t)we * (Hh * Hh) + (size_t)ncl * Hh;
  const int mrow = mquad * 16 + l15;
  const unsigned* pa = hl + (size_t)src * SLOT + (size_t)mrow * HP;

  const int cb = kc * 8;

  f32x4 ac = {0.f, 0.f, 0.f, 0.f}, ah = {0.f, 0.f, 0.f, 0.f};
  #pragma unroll
  for (int h2 = 0; h2 < 2; ++h2) {
    u64 aw[4][4];
    bf16x8 wb0[4], wb1[4];
    #pragma unroll
    for (int u = 0; u < 4; ++u) {
      const int uu = h2 * 4 + u;
      const int k = (cb + uu) * 32 + koff;
      ldhl_issue(pa + k, aw[u]);
      if (kc == 3 && uu == 7) {   // tail: mask B (weight row end)
        bf16x8 z = {0, 0, 0, 0, 0, 0, 0, 0};
        wb0[u] = z; wb1[u] = z;
        if (quad == 0) { wb0[u] = ldB<CB>(Wc, wrow + k);
                         wb1[u] = ldB<CB>(Wh, wrow + k); }
      } else {
        wb0[u] = ldB<CB>(Wc, wrow + k);
        wb1[u] = ldB<CB>(Wh, wrow + k);
      }
    }
    #pragma unroll
    for (int u = 0; u < 4; ++u) {
      bf16x8 a0, a1; unpk(aw[u], a0, a1);
      ac = mfma16(a0, wb0[u], ac); ac = mfma16(a1, wb0[u], ac);
      ah = mfma16(a0, wb1[u], ah); ah = mfma16(a1, wb1[u], ah);
    }
  }

  // split-K reduction through LDS
  #pragma unroll
  for (int r = 0; r < 4; ++r) {
    red[wave][r][lane]     = ac[r];
    red[wave][4 + r][lane] = ah[r];
  }
  __syncthreads();
  if (kc == 0) {
    #pragma unroll
    for (int p = 1; p < 4; ++p) {
      const int w2 = p * 4 + mquad;
      #pragma unroll
      for (int r = 0; r < 4; ++r) {
        ac[r] += red[w2][r][lane];
        ah[r] += red[w2][4 + r][lane];
      }
    }
    const int ne = n0 + l15;
    if (ne < Hh) {
      const int act = g_act[e], leaf = g_leaf[e];
      const unsigned* pi = hl + (size_t)src * SLOT;
      unsigned* pj = hl + (size_t)dst * SLOT;
      #pragma unroll
      for (int r = 0; r < 4; ++r) {
        int me = mquad * 16 + quad * 4 + r;
        size_t idx = (size_t)me * HP + ne;
        float cj = sigm(ac[r]);
        float av = actf(act, ah[r]);
        unsigned wi = ldw(pi + idx);
        float hi_v = bf2f((u16)(wi >> 16)) + bf2f((u16)(wi & 0xFFFFu));
        float hj = sanf(cj * av + (1.0f - ldf(c0b + idx)) * hi_v);  // blend uses c0 (!)
        u16 hb = f2bf(hj);
        u16 lb = f2bf(hj - bf2f(hb));
        stw(pj + idx, ((unsigned)hb << 16) | lb);
        if (leaf) atomicAdd(outb + (size_t)(t * Bb + me) * HP + ne, hj);
      }
    }
  }
}

// ---------------------------------------------------------------------------
// Persistent scan: all 64 timesteps, 6 gbar-separated phases each.
// ---------------------------------------------------------------------------
template<bool CB>
__global__ void __launch_bounds__(STPB, SMIN) scan_kernel(
    const int* __restrict__ inputs, const float* __restrict__ emb,
    const void* __restrict__ wxh, const float* __restrict__ bxh,
    const void* __restrict__ wxc, const float* __restrict__ bxc,
    const void* __restrict__ Wh, const void* __restrict__ Wc,
    unsigned* __restrict__ hl, float* __restrict__ c0b,
    float* __restrict__ outb, unsigned* __restrict__ arr)
{
  __shared__ float red[16][8][64];      // 32 KB
  const int bid = blockIdx.x;
  unsigned ep = 0;

  for (int t = 0; t < Tt; ++t) {
    if (bid < NTILE)
      lev0_body<CB>(bid, t, inputs, emb, wxh, bxh, wxc, bxc, hl, c0b, red);
    gbar(arr, ++ep);
    if (bid < 2 * NTILE) edge_body<CB>(bid, 0, t, Wh, Wc, hl, c0b, outb, red);
    gbar(arr, ++ep);
    if (bid < 3 * NTILE) edge_body<CB>(bid, 2, t, Wh, Wc, hl, c0b, outb, red);
    gbar(arr, ++ep);
    if (bid < 2 * NTILE) edge_body<CB>(bid, 5, t, Wh, Wc, hl, c0b, outb, red);
    gbar(arr, ++ep);
    if (bid < 2 * NTILE) edge_body<CB>(bid, 7, t, Wh, Wc, hl, c0b, outb, red);
    gbar(arr, ++ep);
    if (bid < 2 * NTILE) edge_body<CB>(bid, 9, t, Wh, Wc, hl, c0b, outb, red);
    gbar(arr, ++ep);
  }
}

// ---------------------------------------------------------------------------
// Fallback multi-launch kernels (kernel boundary = sync).
// ---------------------------------------------------------------------------
template<bool CB>
__global__ void __launch_bounds__(STPB, SMIN) lev0_kernel(
    int t, const int* __restrict__ inputs, const float* __restrict__ emb,
    const void* __restrict__ wxh, const float* __restrict__ bxh,
    const void* __restrict__ wxc, const float* __restrict__ bxc,
    unsigned* __restrict__ hl, float* __restrict__ c0b)
{
  __shared__ float red[16][8][64];
  lev0_body<CB>(blockIdx.x, t, inputs, emb, wxh, bxh, wxc, bxc, hl, c0b, red);
}

template<bool CB>
__global__ void __launch_bounds__(STPB, SMIN) edge_kernel(
    int e0, int t, const void* __restrict__ Wh, const void* __restrict__ Wc,
    unsigned* __restrict__ hl, const float* __restrict__ c0b,
    float* __restrict__ outb)
{
  __shared__ float red[16][8][64];
  edge_body<CB>(blockIdx.x, e0, t, Wh, Wc, hl, c0b, outb, red);
}

// fp32 leaf sums (in d_out) -> bf16 * (1/6) into ws.obf; pads stay zero.
__global__ void __launch_bounds__(TPB) cvt_kernel(const float* __restrict__ outb,
                                                  u16* __restrict__ obf) {
  size_t i = ((size_t)blockIdx.x * TPB + threadIdx.x) * 4;
  float4 v = *(const float4*)(outb + i);
  const float s = 1.0f / 6.0f;
  obf[i + 0] = f2bf(sanf(v.x * s));
  obf[i + 1] = f2bf(sanf(v.y * s));
  obf[i + 2] = f2bf(sanf(v.z * s));
  obf[i + 3] = f2bf(sanf(v.w * s));
}

// decoded[4096,10000] = out @ dec_w.T + dec_b, f32 out. 64x64 tile per WG.
__global__ void __launch_bounds__(TPB) decode_kernel(
    const u16* __restrict__ obf, const float* __restrict__ decw,
    const float* __restrict__ decb, float* __restrict__ out)
{
  const int tid = threadIdx.x;
  const int lane = tid & 63, wave = tid >> 6;
  const int l15 = lane & 15, quad = lane >> 4;
  const int bm = blockIdx.x % 64;   // consecutive blocks share bn -> B reuse in L2
  const int bn = blockIdx.x / 64;
  const int mrow = bm * 64 + wave * 16 + l15;
  const u16* pa = obf + (size_t)mrow * HP;
  const float* pb[4];
  #pragma unroll
  for (int j = 0; j < 4; ++j) {
    int v = bn * 64 + j * 16 + l15;
    if (v > Vv - 1) v = Vv - 1;
    pb[j] = decw + (size_t)v * Hh;
  }
  f32x4 acc[4];
  #pragma unroll
  for (int j = 0; j < 4; ++j) acc[j] = (f32x4){0.f, 0.f, 0.f, 0.f};
  const int koff = quad * 8;
  #pragma unroll 2
  for (int c = 0; c < 31; ++c) {
    int k = c * 32 + koff;
    bf16x8 a = ld8(pa + k);
    #pragma unroll
    for (int j = 0; j < 4; ++j) acc[j] = mfma16(a, cvt8(pb[j] + k), acc[j]);
  }
  { // tail: A covers zeroed pads (in-bounds); mask B (dec_w row end)
    int k = 992 + koff;
    bf16x8 a = ld8(pa + k);
    bf16x8 z = {0, 0, 0, 0, 0, 0, 0, 0};
    #pragma unroll
    for (int j = 0; j < 4; ++j) {
      bf16x8 b = z;
      if (quad == 0) b = cvt8(pb[j] + k);
      acc[j] = mfma16(a, b, acc[j]);
    }
  }
  #pragma unroll
  for (int j = 0; j < 4; ++j) {
    int ne = bn * 64 + j * 16 + l15;
    if (ne < Vv) {
      float bv = sanf(decb[ne]);
      #pragma unroll
      for (int r = 0; r < 4; ++r) {
        int me = bm * 64 + wave * 16 + quad * 4 + r;
        out[(size_t)me * Vv + ne] = acc[j][r] + bv;
      }
    }
  }
}

extern "C" void kernel_launch(void* const* d_in, const int* in_sizes, int n_in,
                              void* d_out, int out_size, void* d_ws, size_t ws_size,
                              hipStream_t stream) {
  const int*   inputs = (const int*)d_in[0];
  const float* hidden = (const float*)d_in[1];
  const float* emb    = (const float*)d_in[2];
  const float* wxh    = (const float*)d_in[3];
  const float* bxh    = (const float*)d_in[4];
  const float* wxc    = (const float*)d_in[5];
  const float* bxc    = (const float*)d_in[6];
  const float* Wh     = (const float*)d_in[7];
  const float* Wc     = (const float*)d_in[8];
  const float* decw   = (const float*)d_in[9];
  const float* decb   = (const float*)d_in[10];

  char* ws = (char*)d_ws;
  unsigned* hl  = (unsigned*)(ws);
  float*    c0b = (float*)(ws + OFF_C0);
  u16*      obf = (u16*)(ws + OFF_OBF);
  unsigned* arr = (unsigned*)(ws + OFF_OBF);  // barrier region, overwritten by cvt
  float*    outb = (float*)d_out;   // fp32 leaf sums, consumed before decode

  const bool cached = (ws_size >= (size_t)WS_CACHED);
  u16* wxhb = (u16*)(ws + OFF_WC + WC_WXH);
  u16* wxcb = (u16*)(ws + OFF_WC + WC_WXC);
  u16* Whb  = (u16*)(ws + OFF_WC + WC_WH);
  u16* Wcb  = (u16*)(ws + OFF_WC + WC_WCC);

  // zero hl (pads must be 0) + c0 + barrier arr/rel, and leaf-sum region
  hipMemsetAsync(ws, 0, OFF_OBF, stream);
  hipMemsetAsync(ws + OFF_OBF, 0, 32768, stream);
  hipMemsetAsync(d_out, 0, OUTB_BYTES, stream);

  if (cached) {
    wcvt_kernel<<<(2000000 / 4 + TPB - 1) / TPB, TPB, 0, stream>>>(wxh, wxhb, 2000000);
    wcvt_kernel<<<(2000000 / 4 + TPB - 1) / TPB, TPB, 0, stream>>>(wxc, wxcb, 2000000);
    wcvt_kernel<<<(11000000 / 4 + TPB - 1) / TPB, TPB, 0, stream>>>(Wh, Whb, 11000000);
    wcvt_kernel<<<(11000000 / 4 + TPB - 1) / TPB, TPB, 0, stream>>>(Wc, Wcb, 11000000);
  }
  stage_kernel<<<Bb, TPB, 0, stream>>>(hidden, hl);

  const void* a_wxh = cached ? (const void*)wxhb : (const void*)wxh;
  const void* a_wxc = cached ? (const void*)wxcb : (const void*)wxc;
  const void* a_Wh  = cached ? (const void*)Whb  : (const void*)Wh;
  const void* a_Wc  = cached ? (const void*)Wcb  : (const void*)Wc;
  void* ka[12] = {(void*)&inputs, (void*)&emb, (void*)&a_wxh, (void*)&bxh,
                  (void*)&a_wxc, (void*)&bxc, (void*)&a_Wh, (void*)&a_Wc,
                  (void*)&hl, (void*)&c0b, (void*)&outb, (void*)&arr};
  dim3 sgrid(GPB), sblk(STPB);
  hipError_t ce = cached
    ? hipLaunchCooperativeKernel(scan_kernel<true>,  sgrid, sblk, ka, 0, stream)
    : hipLaunchCooperativeKernel(scan_kernel<false>, sgrid, sblk, ka, 0, stream);

  if (ce != hipSuccess) {
    (void)hipGetLastError();   // clear sticky error; fall back to multi-launch
    static const int lev_off[5] = {0, 2, 5, 7, 9};
    static const int lev_cnt[5] = {2, 3, 2, 2, 2};
    for (int t = 0; t < Tt; ++t) {
      if (cached) {
        lev0_kernel<true><<<NTILE, STPB, 0, stream>>>(t, inputs, emb, wxhb, bxh,
                                                      wxcb, bxc, hl, c0b);
        for (int lev = 0; lev < 5; ++lev)
          edge_kernel<true><<<lev_cnt[lev] * NTILE, STPB, 0, stream>>>(
              lev_off[lev], t, Whb, Wcb, hl, c0b, outb);
      } else {
        lev0_kernel<false><<<NTILE, STPB, 0, stream>>>(t, inputs, emb, wxh, bxh,
                                                       wxc, bxc, hl, c0b);
        for (int lev = 0; lev < 5; ++lev)
          edge_kernel<false><<<lev_cnt[lev] * NTILE, STPB, 0, stream>>>(
              lev_off[lev], t, Wh, Wc, hl, c0b, outb);
      }
    }
  }

  cvt_kernel<<<(Tt * Bb * HP) / (TPB * 4), TPB, 0, stream>>>(outb, obf);
  decode_kernel<<<64 * 157, TPB, 0, stream>>>(obf, decw, decb, (float*)d_out);
}

// Round 8
// 10098.100 us; speedup vs baseline: 1.0073x; 1.0016x over previous
//
#include <hip/hip_runtime.h>

// ============================================================================
// ENAS RNN scan + decode for MI355X (gfx950).  Round 11: force the VGPR
// budget with amdgpu_waves_per_eu(4,4) -- the knob launch_bounds lacks.
//
// Round-10 post-mortem: __launch_bounds__(1024, 4) changed NOTHING (VGPR
// still 64, counters identical): the 2nd arg is a MINIMUM waves/EU -- it can
// only tighten the register cap, not relax the compiler's default 2-block/CU
// (8 waves/EU -> 64 VGPR) target for 16-wave blocks.  The correct knob is
// __attribute__((amdgpu_waves_per_eu(4,4))): max=4 waves/EU tells the
// allocator no second block needs to fit -> 128 VGPRs/wave.  Runtime cost is
// zero (grid 189 <= 256 CUs: there was never a 2nd resident block).
// Staged loads (16 u64 A + 8 dwordx4 B in flight) then live in registers.
// Everything else byte-identical to round 10 (proven barrier, epilogues,
// multi-launch fallback).
//
// MFMA 16x16x32 bf16 layouts (m89-verified):
//   A: lane holds A[m=lane&15][k=(lane>>4)*8 + j], j=0..7
//   B: lane holds B[k=(lane>>4)*8+j][n=lane&15]
//   C/D: col = lane&15, row = (lane>>4)*4 + reg
// ============================================================================

#define TPB 256            // helper kernels
#define STPB 1024          // scan blocks: 16 waves
#define GPB 189            // persistent grid (max level width = 3*NTILE)
#define WPEU __attribute__((amdgpu_waves_per_eu(4, 4)))

#define Tt 64
#define Bb 64
#define Hh 1000
#define Ee 1000
#define Vv 10000
#define HP 1024                 // padded row stride for h buffers
#define SLOT (Bb * HP)          // elems per h slot
#define KW 2000                 // E + H (w_x* row length)
#define NTILE 63                // ceil(1000/16)

typedef unsigned short u16;
typedef unsigned long long u64;
typedef short bf16x8 __attribute__((ext_vector_type(8)));
typedef float f32x4 __attribute__((ext_vector_type(4)));

// ---- ws layout (bytes) ----
// hl (packed hi|lo u32): 12*SLOT*4 = 3,145,728 at ws+0
#define OFF_C0    3145728u     // c0 : 64*HP*4 = 262,144
#define OFF_OBF   3407872u     // obf: 4096*HP*2 (bf16 outputs for decode A)
                               // (first 32 KB double as barrier arr/rel during
                               //  scan; cvt_kernel overwrites them afterwards)
#define OFF_WC    11796480u
#define WC_WXH    0u           // bf16 w_xh  : 2e6*2 = 4,000,000
#define WC_WXC    4000000u     // bf16 w_xc  : 4,000,000
#define WC_WH     8000000u     // bf16 Wh    : 22,000,000
#define WC_WCC    30000000u    // bf16 Wc    : 22,000,000
#define WC_END    52000000u
#define WS_CACHED (OFF_WC + WC_END)   // 63,796,480

#define REL_OFF   (16384u / 4u)       // rel word, u32 index from arr base

// outb (fp32 leaf sums, 4096*1024*4 = 16,777,216 B) lives at the start of
// d_out (163.8 MB fp32 output); consumed by cvt before decode writes d_out.
#define OUTB_BYTES 16777216u

__device__ __forceinline__ float bf2f(u16 u) {
  union { unsigned int i; float f; } c; c.i = ((unsigned int)u) << 16; return c.f;
}
__device__ __forceinline__ u16 f2bf(float f) {
  union { float f; unsigned int i; } c; c.f = f;
  unsigned int u = c.i + 0x7FFFu + ((c.i >> 16) & 1u);
  return (u16)(u >> 16);
}
// Sanitize: clamp to +-16, maps NaN -> -16 (fmaxf/fminf return non-NaN arg).
__device__ __forceinline__ float sanf(float x) {
  return fminf(fmaxf(x, -16.0f), 16.0f);
}
__device__ __forceinline__ f32x4 mfma16(bf16x8 a, bf16x8 b, f32x4 c) {
  return __builtin_amdgcn_mfma_f32_16x16x32_bf16(a, b, c, 0, 0, 0);
}
__device__ __forceinline__ bf16x8 ld8(const u16* p) { return *(const bf16x8*)p; }
__device__ __forceinline__ bf16x8 cvt8(const float* p) {
  float4 v0 = *(const float4*)p, v1 = *(const float4*)(p + 4);
  bf16x8 r;
  r[0] = (short)f2bf(sanf(v0.x)); r[1] = (short)f2bf(sanf(v0.y));
  r[2] = (short)f2bf(sanf(v0.z)); r[3] = (short)f2bf(sanf(v0.w));
  r[4] = (short)f2bf(sanf(v1.x)); r[5] = (short)f2bf(sanf(v1.y));
  r[6] = (short)f2bf(sanf(v1.z)); r[7] = (short)f2bf(sanf(v1.w));
  return r;
}
// B-fragment load: cached bf16 (ws) or in-register f32->bf16. Element offset.
template<bool CB>
__device__ __forceinline__ bf16x8 ldB(const void* base, size_t off) {
  if constexpr (CB) return *(const bf16x8*)((const u16*)base + off);
  else              return cvt8((const float*)base + off);
}

// ---- coherent (LLC) access for mutable scan state ----
// A-fragment loads: 4x relaxed agent-scope u64 atomic loads (compile to
// global_load_dwordx2 sc0 sc1) -- compiler-tracked, pipeline-able, safe.
__device__ __forceinline__ void ldhl_issue(const unsigned* p, u64* w) {
  const u64* q = (const u64*)p;   // 8B-aligned: element offsets multiple of 8
  w[0] = __hip_atomic_load(q + 0, __ATOMIC_RELAXED, __HIP_MEMORY_SCOPE_AGENT);
  w[1] = __hip_atomic_load(q + 1, __ATOMIC_RELAXED, __HIP_MEMORY_SCOPE_AGENT);
  w[2] = __hip_atomic_load(q + 2, __ATOMIC_RELAXED, __HIP_MEMORY_SCOPE_AGENT);
  w[3] = __hip_atomic_load(q + 3, __ATOMIC_RELAXED, __HIP_MEMORY_SCOPE_AGENT);
}
__device__ __forceinline__ void unpk(const u64* w, bf16x8& hi, bf16x8& lo) {
  #pragma unroll
  for (int j = 0; j < 4; ++j) {
    unsigned e0 = (unsigned)w[j], e1 = (unsigned)(w[j] >> 32);
    hi[2 * j]     = (short)(u16)(e0 >> 16); lo[2 * j]     = (short)(u16)e0;
    hi[2 * j + 1] = (short)(u16)(e1 >> 16); lo[2 * j + 1] = (short)(u16)e1;
  }
}
__device__ __forceinline__ unsigned ldw(const unsigned* p) {
  return __hip_atomic_load((unsigned*)p, __ATOMIC_RELAXED, __HIP_MEMORY_SCOPE_AGENT);
}
__device__ __forceinline__ void stw(unsigned* p, unsigned v) {
  __hip_atomic_store(p, v, __ATOMIC_RELAXED, __HIP_MEMORY_SCOPE_AGENT);
}
__device__ __forceinline__ float ldf(const float* p) {
  return __hip_atomic_load((float*)p, __ATOMIC_RELAXED, __HIP_MEMORY_SCOPE_AGENT);
}
__device__ __forceinline__ void stf(float* p, float v) {
  __hip_atomic_store(p, v, __ATOMIC_RELAXED, __HIP_MEMORY_SCOPE_AGENT);
}

__device__ __forceinline__ float sigm(float x) { return 1.0f / (1.0f + __expf(-x)); }
__device__ __forceinline__ float tanh_(float x) {
  float e = __expf(-2.0f * fabsf(x));
  float t = (1.0f - e) / (1.0f + e);
  return x < 0.0f ? -t : t;
}
__device__ __forceinline__ float actf(int a, float x) {
  if (a == 0) return fmaxf(x, 0.0f);   // relu
  if (a == 1) return tanh_(x);         // tanh
  if (a == 2) return sigm(x);          // sigmoid
  return x;                            // identity
}

// Edge schedule, grouped by DAG level (positions 0..10).
// act: 0=relu 1=tanh 2=sigmoid 3=identity
__constant__ short g_e[11]    = {0, 1, 2, 3, 10, 4, 5, 6, 7, 8, 9};
__constant__ short g_src[11]  = {0, 0, 1, 1, 6, 2, 2, 3, 3, 4, 4};
__constant__ short g_dst[11]  = {1, 6, 2, 8, 7, 3, 9, 4, 10, 5, 11};
__constant__ short g_act[11]  = {0, 1, 0, 2, 1, 1, 0, 3, 1, 0, 2};
__constant__ short g_leaf[11] = {0, 0, 0, 1, 1, 0, 1, 0, 1, 1, 1};

// f32 -> sanitized bf16 (weight cache). n divisible by 4.
__global__ void __launch_bounds__(TPB) wcvt_kernel(const float* __restrict__ src,
                                                   u16* __restrict__ dst, int n) {
  int i = (blockIdx.x * TPB + threadIdx.x) * 4;
  if (i < n) {
    float4 v = *(const float4*)(src + i);
    dst[i + 0] = f2bf(sanf(v.x));
    dst[i + 1] = f2bf(sanf(v.y));
    dst[i + 2] = f2bf(sanf(v.z));
    dst[i + 3] = f2bf(sanf(v.w));
  }
}

// hidden [64,1000] f32 -> h slot 11 packed hi|lo (pads zeroed by memset).
__global__ void __launch_bounds__(TPB) stage_kernel(const float* __restrict__ hidden,
                                                    unsigned* __restrict__ hl) {
  int b = blockIdx.x;
  for (int k = threadIdx.x; k < Hh; k += TPB) {
    float x = sanf(hidden[b * Hh + k]);
    u16 h = f2bf(x);
    u16 l = f2bf(x - bf2f(h));
    hl[11 * SLOT + b * HP + k] = ((unsigned)h << 16) | l;
  }
}

// ---------------------------------------------------------------------------
// Contention-free grid barrier (round-8 proven).
// ---------------------------------------------------------------------------
__device__ __forceinline__ void gbar(unsigned* arr, unsigned ep) {
  asm volatile("s_waitcnt vmcnt(0) lgkmcnt(0)" ::: "memory");
  __syncthreads();
  const int tid = threadIdx.x;
  if (blockIdx.x == 0) {
    if (tid >= 1 && tid < GPB) {
      while (ldw(arr + tid * 16) < ep) __builtin_amdgcn_s_sleep(2);
    }
    __syncthreads();
    if (tid == 0) stw(arr + REL_OFF, ep);
  } else {
    if (tid == 0) {
      stw(arr + blockIdx.x * 16, ep);
      while (ldw(arr + REL_OFF) < ep) __builtin_amdgcn_s_sleep(2);
    }
    __syncthreads();
  }
  __builtin_amdgcn_sched_barrier(0);
  asm volatile("" ::: "memory");
}

// ---------------------------------------------------------------------------
// Per-level bodies.  1024 threads = 16 waves = kc (K-chunk, 4) x mquad (m, 4).
// Each wave owns 8 K-units; processed as two 4-unit stages: {issue 16 A +
// 8 B loads into register arrays} -> {unpack + 16 MFMA}.  Split-K partials
// reduced through 32 KB LDS, epilogue by kc==0 waves.
// ---------------------------------------------------------------------------
template<bool CB>
__device__ __forceinline__ void lev0_body(
    const int bid, const int t,
    const int* __restrict__ inputs, const float* __restrict__ emb,
    const void* __restrict__ wxh, const float* __restrict__ bxh,
    const void* __restrict__ wxc, const float* __restrict__ bxc,
    unsigned* __restrict__ hl, float* __restrict__ c0b,
    float (*red)[8][64])
{
  const int tid = threadIdx.x;
  const int lane = tid & 63, wave = tid >> 6;
  const int mquad = wave & 3, kc = wave >> 2;
  const int l15 = lane & 15, quad = lane >> 4;
  const int koff = quad * 8;

  const int n0 = bid * 16;                      // 63 tiles
  const int nrow = n0 + l15;
  const int ncl = nrow < Hh ? nrow : Hh - 1;
  const size_t wrow = (size_t)ncl * KW;
  const int mrow = mquad * 16 + l15;
  int ix = inputs[t * Bb + mrow];
  ix = ix < 0 ? 0 : (ix >= Vv ? Vv - 1 : ix);   // defensive clamp
  const float* px = emb + (size_t)ix * Ee;
  const unsigned* ph = hl + 11 * SLOT + (size_t)mrow * HP;

  const int cb = kc * 8;

  f32x4 ac = {0.f, 0.f, 0.f, 0.f}, ah = {0.f, 0.f, 0.f, 0.f};

  // phase 1: x part (k 0..999), A = emb converted f32->bf16 (normal cached
  // loads, compiler-pipelined).  Unit 7 of kc==3 is the tail: A masked to
  // quad==0 (embedding row end); B row len 2000 -> always in-bounds.
  #pragma unroll 2
  for (int u = 0; u < 8; ++u) {
    int k = (cb + u) * 32 + koff;
    bf16x8 a;
    if (kc == 3 && u == 7) {
      bf16x8 z = {0, 0, 0, 0, 0, 0, 0, 0};
      a = z;
      if (quad == 0) a = cvt8(px + k);
    } else {
      a = cvt8(px + k);
    }
    ac = mfma16(a, ldB<CB>(wxc, wrow + k), ac);
    ah = mfma16(a, ldB<CB>(wxh, wrow + k), ah);
  }

  // phase 2: h_prev part (hi + lo from packed u32), B cols 1000..1999.
  // Two 4-unit stages; A via staged u64 atomic loads for deep MLP.
  #pragma unroll
  for (int h2 = 0; h2 < 2; ++h2) {
    u64 aw[4][4];
    bf16x8 wb0[4], wb1[4];
    #pragma unroll
    for (int u = 0; u < 4; ++u) {
      const int uu = h2 * 4 + u;
      const int k = (cb + uu) * 32 + koff;
      ldhl_issue(ph + k, aw[u]);
      if (kc == 3 && uu == 7) {   // tail: mask B (w_x* row end)
        bf16x8 z = {0, 0, 0, 0, 0, 0, 0, 0};
        wb0[u] = z; wb1[u] = z;
        if (quad == 0) { wb0[u] = ldB<CB>(wxc, wrow + 1000 + k);
                         wb1[u] = ldB<CB>(wxh, wrow + 1000 + k); }
      } else {
        wb0[u] = ldB<CB>(wxc, wrow + 1000 + k);
        wb1[u] = ldB<CB>(wxh, wrow + 1000 + k);
      }
    }
    #pragma unroll
    for (int u = 0; u < 4; ++u) {
      bf16x8 a0, a1; unpk(aw[u], a0, a1);
      ac = mfma16(a0, wb0[u], ac); ac = mfma16(a1, wb0[u], ac);
      ah = mfma16(a0, wb1[u], ah); ah = mfma16(a1, wb1[u], ah);
    }
  }

  // split-K reduction through LDS
  #pragma unroll
  for (int r = 0; r < 4; ++r) {
    red[wave][r][lane]     = ac[r];
    red[wave][4 + r][lane] = ah[r];
  }
  __syncthreads();
  if (kc == 0) {
    #pragma unroll
    for (int p = 1; p < 4; ++p) {
      const int w2 = p * 4 + mquad;
      #pragma unroll
      for (int r = 0; r < 4; ++r) {
        ac[r] += red[w2][r][lane];
        ah[r] += red[w2][4 + r][lane];
      }
    }
    const int ne = n0 + l15;
    if (ne < Hh) {
      float bxcv = sanf(bxc[ne]), bxhv = sanf(bxh[ne]);
      #pragma unroll
      for (int r = 0; r < 4; ++r) {
        int me = mquad * 16 + quad * 4 + r;
        size_t idx = (size_t)me * HP + ne;
        float c0v = sigm(ac[r] + bxcv);
        unsigned wprev = ldw(hl + 11 * SLOT + idx);
        float hp = bf2f((u16)(wprev >> 16)) + bf2f((u16)(wprev & 0xFFFFu));
        float h0 = sanf(c0v * tanh_(ah[r] + bxhv) + (1.0f - c0v) * hp);
        stf(c0b + idx, c0v);
        u16 hb = f2bf(h0);
        u16 lb = f2bf(h0 - bf2f(hb));
        stw(hl + idx, ((unsigned)hb << 16) | lb);   // slot 0
      }
    }
  }
}

template<bool CB>
__device__ __forceinline__ void edge_body(
    const int bid, const int e0, const int t,
    const void* __restrict__ Wh, const void* __restrict__ Wc,
    unsigned* __restrict__ hl, const float* __restrict__ c0b,
    float* __restrict__ outb, float (*red)[8][64])
{
  const int tid = threadIdx.x;
  const int lane = tid & 63, wave = tid >> 6;
  const int mquad = wave & 3, kc = wave >> 2;
  const int l15 = lane & 15, quad = lane >> 4;
  const int koff = quad * 8;

  const int er = bid / NTILE;
  const int e = e0 + er;
  const int n0 = (bid - er * NTILE) * 16;
  const int we = g_e[e], src = g_src[e], dst = g_dst[e];
  const int nrow = n0 + l15;
  const int ncl = nrow < Hh ? nrow : Hh - 1;
  const size_t wrow = (size_t)we * (Hh * Hh) + (size_t)ncl * Hh;
  const int mrow = mquad * 16 + l15;
  const unsigned* pa = hl + (size_t)src * SLOT + (size_t)mrow * HP;

  const int cb = kc * 8;

  f32x4 ac = {0.f, 0.f, 0.f, 0.f}, ah = {0.f, 0.f, 0.f, 0.f};
  #pragma unroll
  for (int h2 = 0; h2 < 2; ++h2) {
    u64 aw[4][4];
    bf16x8 wb0[4], wb1[4];
    #pragma unroll
    for (int u = 0; u < 4; ++u) {
      const int uu = h2 * 4 + u;
      const int k = (cb + uu) * 32 + koff;
      ldhl_issue(pa + k, aw[u]);
      if (kc == 3 && uu == 7) {   // tail: mask B (weight row end)
        bf16x8 z = {0, 0, 0, 0, 0, 0, 0, 0};
        wb0[u] = z; wb1[u] = z;
        if (quad == 0) { wb0[u] = ldB<CB>(Wc, wrow + k);
                         wb1[u] = ldB<CB>(Wh, wrow + k); }
      } else {
        wb0[u] = ldB<CB>(Wc, wrow + k);
        wb1[u] = ldB<CB>(Wh, wrow + k);
      }
    }
    #pragma unroll
    for (int u = 0; u < 4; ++u) {
      bf16x8 a0, a1; unpk(aw[u], a0, a1);
      ac = mfma16(a0, wb0[u], ac); ac = mfma16(a1, wb0[u], ac);
      ah = mfma16(a0, wb1[u], ah); ah = mfma16(a1, wb1[u], ah);
    }
  }

  // split-K reduction through LDS
  #pragma unroll
  for (int r = 0; r < 4; ++r) {
    red[wave][r][lane]     = ac[r];
    red[wave][4 + r][lane] = ah[r];
  }
  __syncthreads();
  if (kc == 0) {
    #pragma unroll
    for (int p = 1; p < 4; ++p) {
      const int w2 = p * 4 + mquad;
      #pragma unroll
      for (int r = 0; r < 4; ++r) {
        ac[r] += red[w2][r][lane];
        ah[r] += red[w2][4 + r][lane];
      }
    }
    const int ne = n0 + l15;
    if (ne < Hh) {
      const int act = g_act[e], leaf = g_leaf[e];
      const unsigned* pi = hl + (size_t)src * SLOT;
      unsigned* pj = hl + (size_t)dst * SLOT;
      #pragma unroll
      for (int r = 0; r < 4; ++r) {
        int me = mquad * 16 + quad * 4 + r;
        size_t idx = (size_t)me * HP + ne;
        float cj = sigm(ac[r]);
        float av = actf(act, ah[r]);
        unsigned wi = ldw(pi + idx);
        float hi_v = bf2f((u16)(wi >> 16)) + bf2f((u16)(wi & 0xFFFFu));
        float hj = sanf(cj * av + (1.0f - ldf(c0b + idx)) * hi_v);  // blend uses c0 (!)
        u16 hb = f2bf(hj);
        u16 lb = f2bf(hj - bf2f(hb));
        stw(pj + idx, ((unsigned)hb << 16) | lb);
        if (leaf) atomicAdd(outb + (size_t)(t * Bb + me) * HP + ne, hj);
      }
    }
  }
}

// ---------------------------------------------------------------------------
// Persistent scan: all 64 timesteps, 6 gbar-separated phases each.
// ---------------------------------------------------------------------------
template<bool CB>
__global__ void __launch_bounds__(STPB) WPEU scan_kernel(
    const int* __restrict__ inputs, const float* __restrict__ emb,
    const void* __restrict__ wxh, const float* __restrict__ bxh,
    const void* __restrict__ wxc, const float* __restrict__ bxc,
    const void* __restrict__ Wh, const void* __restrict__ Wc,
    unsigned* __restrict__ hl, float* __restrict__ c0b,
    float* __restrict__ outb, unsigned* __restrict__ arr)
{
  __shared__ float red[16][8][64];      // 32 KB
  const int bid = blockIdx.x;
  unsigned ep = 0;

  for (int t = 0; t < Tt; ++t) {
    if (bid < NTILE)
      lev0_body<CB>(bid, t, inputs, emb, wxh, bxh, wxc, bxc, hl, c0b, red);
    gbar(arr, ++ep);
    if (bid < 2 * NTILE) edge_body<CB>(bid, 0, t, Wh, Wc, hl, c0b, outb, red);
    gbar(arr, ++ep);
    if (bid < 3 * NTILE) edge_body<CB>(bid, 2, t, Wh, Wc, hl, c0b, outb, red);
    gbar(arr, ++ep);
    if (bid < 2 * NTILE) edge_body<CB>(bid, 5, t, Wh, Wc, hl, c0b, outb, red);
    gbar(arr, ++ep);
    if (bid < 2 * NTILE) edge_body<CB>(bid, 7, t, Wh, Wc, hl, c0b, outb, red);
    gbar(arr, ++ep);
    if (bid < 2 * NTILE) edge_body<CB>(bid, 9, t, Wh, Wc, hl, c0b, outb, red);
    gbar(arr, ++ep);
  }
}

// ---------------------------------------------------------------------------
// Fallback multi-launch kernels (kernel boundary = sync).
// ---------------------------------------------------------------------------
template<bool CB>
__global__ void __launch_bounds__(STPB) WPEU lev0_kernel(
    int t, const int* __restrict__ inputs, const float* __restrict__ emb,
    const void* __restrict__ wxh, const float* __restrict__ bxh,
    const void* __restrict__ wxc, const float* __restrict__ bxc,
    unsigned* __restrict__ hl, float* __restrict__ c0b)
{
  __shared__ float red[16][8][64];
  lev0_body<CB>(blockIdx.x, t, inputs, emb, wxh, bxh, wxc, bxc, hl, c0b, red);
}

template<bool CB>
__global__ void __launch_bounds__(STPB) WPEU edge_kernel(
    int e0, int t, const void* __restrict__ Wh, const void* __restrict__ Wc,
    unsigned* __restrict__ hl, const float* __restrict__ c0b,
    float* __restrict__ outb)
{
  __shared__ float red[16][8][64];
  edge_body<CB>(blockIdx.x, e0, t, Wh, Wc, hl, c0b, outb, red);
}

// fp32 leaf sums (in d_out) -> bf16 * (1/6) into ws.obf; pads stay zero.
__global__ void __launch_bounds__(TPB) cvt_kernel(const float* __restrict__ outb,
                                                  u16* __restrict__ obf) {
  size_t i = ((size_t)blockIdx.x * TPB + threadIdx.x) * 4;
  float4 v = *(const float4*)(outb + i);
  const float s = 1.0f / 6.0f;
  obf[i + 0] = f2bf(sanf(v.x * s));
  obf[i + 1] = f2bf(sanf(v.y * s));
  obf[i + 2] = f2bf(sanf(v.z * s));
  obf[i + 3] = f2bf(sanf(v.w * s));
}

// decoded[4096,10000] = out @ dec_w.T + dec_b, f32 out. 64x64 tile per WG.
__global__ void __launch_bounds__(TPB) decode_kernel(
    const u16* __restrict__ obf, const float* __restrict__ decw,
    const float* __restrict__ decb, float* __restrict__ out)
{
  const int tid = threadIdx.x;
  const int lane = tid & 63, wave = tid >> 6;
  const int l15 = lane & 15, quad = lane >> 4;
  const int bm = blockIdx.x % 64;   // consecutive blocks share bn -> B reuse in L2
  const int bn = blockIdx.x / 64;
  const int mrow = bm * 64 + wave * 16 + l15;
  const u16* pa = obf + (size_t)mrow * HP;
  const float* pb[4];
  #pragma unroll
  for (int j = 0; j < 4; ++j) {
    int v = bn * 64 + j * 16 + l15;
    if (v > Vv - 1) v = Vv - 1;
    pb[j] = decw + (size_t)v * Hh;
  }
  f32x4 acc[4];
  #pragma unroll
  for (int j = 0; j < 4; ++j) acc[j] = (f32x4){0.f, 0.f, 0.f, 0.f};
  const int koff = quad * 8;
  #pragma unroll 2
  for (int c = 0; c < 31; ++c) {
    int k = c * 32 + koff;
    bf16x8 a = ld8(pa + k);
    #pragma unroll
    for (int j = 0; j < 4; ++j) acc[j] = mfma16(a, cvt8(pb[j] + k), acc[j]);
  }
  { // tail: A covers zeroed pads (in-bounds); mask B (dec_w row end)
    int k = 992 + koff;
    bf16x8 a = ld8(pa + k);
    bf16x8 z = {0, 0, 0, 0, 0, 0, 0, 0};
    #pragma unroll
    for (int j = 0; j < 4; ++j) {
      bf16x8 b = z;
      if (quad == 0) b = cvt8(pb[j] + k);
      acc[j] = mfma16(a, b, acc[j]);
    }
  }
  #pragma unroll
  for (int j = 0; j < 4; ++j) {
    int ne = bn * 64 + j * 16 + l15;
    if (ne < Vv) {
      float bv = sanf(decb[ne]);
      #pragma unroll
      for (int r = 0; r < 4; ++r) {
        int me = bm * 64 + wave * 16 + quad * 4 + r;
        out[(size_t)me * Vv + ne] = acc[j][r] + bv;
      }
    }
  }
}

extern "C" void kernel_launch(void* const* d_in, const int* in_sizes, int n_in,
                              void* d_out, int out_size, void* d_ws, size_t ws_size,
                              hipStream_t stream) {
  const int*   inputs = (const int*)d_in[0];
  const float* hidden = (const float*)d_in[1];
  const float* emb    = (const float*)d_in[2];
  const float* wxh    = (const float*)d_in[3];
  const float* bxh    = (const float*)d_in[4];
  const float* wxc    = (const float*)d_in[5];
  const float* bxc    = (const float*)d_in[6];
  const float* Wh     = (const float*)d_in[7];
  const float* Wc     = (const float*)d_in[8];
  const float* decw   = (const float*)d_in[9];
  const float* decb   = (const float*)d_in[10];

  char* ws = (char*)d_ws;
  unsigned* hl  = (unsigned*)(ws);
  float*    c0b = (float*)(ws + OFF_C0);
  u16*      obf = (u16*)(ws + OFF_OBF);
  unsigned* arr = (unsigned*)(ws + OFF_OBF);  // barrier region, overwritten by cvt
  float*    outb = (float*)d_out;   // fp32 leaf sums, consumed before decode

  const bool cached = (ws_size >= (size_t)WS_CACHED);
  u16* wxhb = (u16*)(ws + OFF_WC + WC_WXH);
  u16* wxcb = (u16*)(ws + OFF_WC + WC_WXC);
  u16* Whb  = (u16*)(ws + OFF_WC + WC_WH);
  u16* Wcb  = (u16*)(ws + OFF_WC + WC_WCC);

  // zero hl (pads must be 0) + c0 + barrier arr/rel, and leaf-sum region
  hipMemsetAsync(ws, 0, OFF_OBF, stream);
  hipMemsetAsync(ws + OFF_OBF, 0, 32768, stream);
  hipMemsetAsync(d_out, 0, OUTB_BYTES, stream);

  if (cached) {
    wcvt_kernel<<<(2000000 / 4 + TPB - 1) / TPB, TPB, 0, stream>>>(wxh, wxhb, 2000000);
    wcvt_kernel<<<(2000000 / 4 + TPB - 1) / TPB, TPB, 0, stream>>>(wxc, wxcb, 2000000);
    wcvt_kernel<<<(11000000 / 4 + TPB - 1) / TPB, TPB, 0, stream>>>(Wh, Whb, 11000000);
    wcvt_kernel<<<(11000000 / 4 + TPB - 1) / TPB, TPB, 0, stream>>>(Wc, Wcb, 11000000);
  }
  stage_kernel<<<Bb, TPB, 0, stream>>>(hidden, hl);

  const void* a_wxh = cached ? (const void*)wxhb : (const void*)wxh;
  const void* a_wxc = cached ? (const void*)wxcb : (const void*)wxc;
  const void* a_Wh  = cached ? (const void*)Whb  : (const void*)Wh;
  const void* a_Wc  = cached ? (const void*)Wcb  : (const void*)Wc;
  void* ka[12] = {(void*)&inputs, (void*)&emb, (void*)&a_wxh, (void*)&bxh,
                  (void*)&a_wxc, (void*)&bxc, (void*)&a_Wh, (void*)&a_Wc,
                  (void*)&hl, (void*)&c0b, (void*)&outb, (void*)&arr};
  dim3 sgrid(GPB), sblk(STPB);
  hipError_t ce = cached
    ? hipLaunchCooperativeKernel(scan_kernel<true>,  sgrid, sblk, ka, 0, stream)
    : hipLaunchCooperativeKernel(scan_kernel<false>, sgrid, sblk, ka, 0, stream);

  if (ce != hipSuccess) {
    (void)hipGetLastError();   // clear sticky error; fall back to multi-launch
    static const int lev_off[5] = {0, 2, 5, 7, 9};
    static const int lev_cnt[5] = {2, 3, 2, 2, 2};
    for (int t = 0; t < Tt; ++t) {
      if (cached) {
        lev0_kernel<true><<<NTILE, STPB, 0, stream>>>(t, inputs, emb, wxhb, bxh,
                                                      wxcb, bxc, hl, c0b);
        for (int lev = 0; lev < 5; ++lev)
          edge_kernel<true><<<lev_cnt[lev] * NTILE, STPB, 0, stream>>>(
              lev_off[lev], t, Whb, Wcb, hl, c0b, outb);
      } else {
        lev0_kernel<false><<<NTILE, STPB, 0, stream>>>(t, inputs, emb, wxh, bxh,
                                                       wxc, bxc, hl, c0b);
        for (int lev = 0; lev < 5; ++lev)
          edge_kernel<false><<<lev_cnt[lev] * NTILE, STPB, 0, stream>>>(
              lev_off[lev], t, Wh, Wc, hl, c0b, outb);
      }
    }
  }

  cvt_kernel<<<(Tt * Bb * HP) / (TPB * 4), TPB, 0, stream>>>(outb, obf);
  decode_kernel<<<64 * 157, TPB, 0, stream>>>(obf, decw, decb, (float*)d_out);
}

// Round 9
// 5746.689 us; speedup vs baseline: 1.7700x; 1.7572x over previous
//
#include <hip/hip_runtime.h>

// ============================================================================
// ENAS RNN scan + decode for MI355X (gfx950).  Round 12: back to the proven
// multi-launch structure (round-2, 6943us), with 4x the waves per level.
//
// Rounds 6-11 post-mortem: persistent-kernel line abandoned -- barrier fixed
// (r8) but per-level work is fetch-latency-bound and the compiler refuses to
// hold staged loads in registers (VGPR pinned at 64 across launch_bounds and
// amdgpu_waves_per_eu attempts; 3 identical null results).
//
// This round: round-2 multi-launch + finer decomposition.
//   - M-split x4: each block owns ONE 16x16 output tile (not 64x16).
//   - split-K x16: wave kc (0..15) does K-units {2kc, 2kc+1} -- ~8 loads
//     issued back-to-back per wave, natural MLP without staging arrays.
//   - grid per level: 63 tiles x 4 m-chunks x lev_cnt = 252..756 blocks ->
//     all 256 CUs busy at 2 blocks/CU (32 waves/CU), vs 126 blocks before.
//   - 16-way split-K reduction: two short LDS stages (16 waves write, 8
//     half-waves tree-sum columns, wave 0 epilogue).
// Math identical to round 2 up to f32 reassociation.  No persistent kernel,
// no custom barrier, no cache-bypass tricks -- kernel boundary is the sync.
//
// MFMA 16x16x32 bf16 layouts (m89-verified):
//   A: lane holds A[m=lane&15][k=(lane>>4)*8 + j], j=0..7
//   B: lane holds B[k=(lane>>4)*8+j][n=lane&15]
//   C/D: col = lane&15, row = (lane>>4)*4 + reg
// ============================================================================

#define TPB 256            // helper kernels
#define STPB 1024          // scan kernels: 16 waves (= 16 K-chunks)

#define Tt 64
#define Bb 64
#define Hh 1000
#define Ee 1000
#define Vv 10000
#define HP 1024                 // padded row stride for h buffers
#define SLOT (Bb * HP)          // elems per h slot
#define KW 2000                 // E + H (w_x* row length)
#define NTILE 63                // ceil(1000/16)
#define MB4 (NTILE * 4)         // blocks per edge: 63 n-tiles x 4 m-chunks

typedef unsigned short u16;
typedef short bf16x8 __attribute__((ext_vector_type(8)));
typedef float f32x4 __attribute__((ext_vector_type(4)));

// ---- ws layout (bytes) ----
#define OFF_HLO   1572864u     // hhi: 12*SLOT*2
#define OFF_C0    3145728u     // hlo: 12*SLOT*2
#define OFF_OBF   3407872u     // c0 : 64*HP*4
#define OFF_WC    11796480u    // obf: 4096*HP*2 (bf16 outputs for decode A)
#define WC_WXH    0u           // bf16 w_xh  : 2e6*2 = 4,000,000
#define WC_WXC    4000000u     // bf16 w_xc  : 4,000,000
#define WC_WH     8000000u     // bf16 Wh    : 22,000,000
#define WC_WCC    30000000u    // bf16 Wc    : 22,000,000
#define WC_END    52000000u
#define WS_CACHED (OFF_WC + WC_END)   // 63,796,480

// outb (fp32 leaf sums, 4096*1024*4 = 16,777,216 B) lives at the start of
// d_out (163.8 MB fp32 output); consumed by cvt before decode writes d_out.
#define OUTB_BYTES 16777216u

__device__ __forceinline__ float bf2f(u16 u) {
  union { unsigned int i; float f; } c; c.i = ((unsigned int)u) << 16; return c.f;
}
__device__ __forceinline__ u16 f2bf(float f) {
  union { float f; unsigned int i; } c; c.f = f;
  unsigned int u = c.i + 0x7FFFu + ((c.i >> 16) & 1u);
  return (u16)(u >> 16);
}
// Sanitize: clamp to +-16, maps NaN -> -16 (fmaxf/fminf return non-NaN arg).
__device__ __forceinline__ float sanf(float x) {
  return fminf(fmaxf(x, -16.0f), 16.0f);
}
__device__ __forceinline__ f32x4 mfma16(bf16x8 a, bf16x8 b, f32x4 c) {
  return __builtin_amdgcn_mfma_f32_16x16x32_bf16(a, b, c, 0, 0, 0);
}
__device__ __forceinline__ bf16x8 ld8(const u16* p) { return *(const bf16x8*)p; }
__device__ __forceinline__ bf16x8 cvt8(const float* p) {
  float4 v0 = *(const float4*)p, v1 = *(const float4*)(p + 4);
  bf16x8 r;
  r[0] = (short)f2bf(sanf(v0.x)); r[1] = (short)f2bf(sanf(v0.y));
  r[2] = (short)f2bf(sanf(v0.z)); r[3] = (short)f2bf(sanf(v0.w));
  r[4] = (short)f2bf(sanf(v1.x)); r[5] = (short)f2bf(sanf(v1.y));
  r[6] = (short)f2bf(sanf(v1.z)); r[7] = (short)f2bf(sanf(v1.w));
  return r;
}
// B-fragment load: cached bf16 (ws) or in-register f32->bf16. Element offset.
template<bool CB>
__device__ __forceinline__ bf16x8 ldB(const void* base, size_t off) {
  if constexpr (CB) return *(const bf16x8*)((const u16*)base + off);
  else              return cvt8((const float*)base + off);
}

__device__ __forceinline__ float sigm(float x) { return 1.0f / (1.0f + __expf(-x)); }
__device__ __forceinline__ float tanh_(float x) {
  float e = __expf(-2.0f * fabsf(x));
  float t = (1.0f - e) / (1.0f + e);
  return x < 0.0f ? -t : t;
}
__device__ __forceinline__ float actf(int a, float x) {
  if (a == 0) return fmaxf(x, 0.0f);   // relu
  if (a == 1) return tanh_(x);         // tanh
  if (a == 2) return sigm(x);          // sigmoid
  return x;                            // identity
}

// Edge schedule, grouped by DAG level (positions 0..10).
// act: 0=relu 1=tanh 2=sigmoid 3=identity
__constant__ short g_e[11]    = {0, 1, 2, 3, 10, 4, 5, 6, 7, 8, 9};
__constant__ short g_src[11]  = {0, 0, 1, 1, 6, 2, 2, 3, 3, 4, 4};
__constant__ short g_dst[11]  = {1, 6, 2, 8, 7, 3, 9, 4, 10, 5, 11};
__constant__ short g_act[11]  = {0, 1, 0, 2, 1, 1, 0, 3, 1, 0, 2};
__constant__ short g_leaf[11] = {0, 0, 0, 1, 1, 0, 1, 0, 1, 1, 1};

// f32 -> sanitized bf16 (weight cache). n divisible by 4.
__global__ void __launch_bounds__(TPB) wcvt_kernel(const float* __restrict__ src,
                                                   u16* __restrict__ dst, int n) {
  int i = (blockIdx.x * TPB + threadIdx.x) * 4;
  if (i < n) {
    float4 v = *(const float4*)(src + i);
    dst[i + 0] = f2bf(sanf(v.x));
    dst[i + 1] = f2bf(sanf(v.y));
    dst[i + 2] = f2bf(sanf(v.z));
    dst[i + 3] = f2bf(sanf(v.w));
  }
}

// hidden [64,1000] f32 -> h slot 11 hi/lo (pads already zeroed by memset).
__global__ void __launch_bounds__(TPB) stage_kernel(const float* __restrict__ hidden,
                                                    u16* __restrict__ hhi,
                                                    u16* __restrict__ hlo) {
  int b = blockIdx.x;
  for (int k = threadIdx.x; k < Hh; k += TPB) {
    float x = sanf(hidden[b * Hh + k]);
    u16 h = f2bf(x);
    hhi[11 * SLOT + b * HP + k] = h;
    hlo[11 * SLOT + b * HP + k] = f2bf(x - bf2f(h));
  }
}

// ---------------------------------------------------------------------------
// lev0: x/h cell.  Block = one 16x16 tile (n-tile nt, m-chunk mc); 16 waves =
// 16 K-chunks; wave kc does K-units {2kc, 2kc+1} of BOTH phases (unit 31 =
// tail).  16-way LDS reduction, epilogue by wave 0.
// ---------------------------------------------------------------------------
template<bool CB>
__global__ void __launch_bounds__(STPB) lev0_kernel(
    int t, const int* __restrict__ inputs, const float* __restrict__ emb,
    const void* __restrict__ wxh, const float* __restrict__ bxh,
    const void* __restrict__ wxc, const float* __restrict__ bxc,
    u16* __restrict__ hhi, u16* __restrict__ hlo, float* __restrict__ c0b)
{
  __shared__ float red[16][8][64];      // 32 KB
  const int tid = threadIdx.x;
  const int lane = tid & 63, kc = tid >> 6;     // wave index = K-chunk
  const int l15 = lane & 15, quad = lane >> 4;
  const int koff = quad * 8;

  const int nt = blockIdx.x % NTILE, mc = blockIdx.x / NTILE;
  const int n0 = nt * 16;
  const int nrow = n0 + l15;
  const int ncl = nrow < Hh ? nrow : Hh - 1;
  const size_t wrow = (size_t)ncl * KW;
  const int mrow = mc * 16 + l15;
  int ix = inputs[t * Bb + mrow];
  ix = ix < 0 ? 0 : (ix >= Vv ? Vv - 1 : ix);   // defensive clamp
  const float* px = emb + (size_t)ix * Ee;
  const u16* phh = hhi + 11 * SLOT + (size_t)mrow * HP;
  const u16* phl = hlo + 11 * SLOT + (size_t)mrow * HP;

  f32x4 ac = {0.f, 0.f, 0.f, 0.f}, ah = {0.f, 0.f, 0.f, 0.f};
  #pragma unroll
  for (int s = 0; s < 2; ++s) {
    const int u = kc * 2 + s;                       // 0..31
    const int k = (u < 31 ? u * 32 : 992) + koff;
    // phase 1: x part (k 0..999).  u31: mask A (emb row end); B in-bounds.
    {
      bf16x8 a;
      if (u == 31) {
        bf16x8 z = {0, 0, 0, 0, 0, 0, 0, 0};
        a = z;
        if (quad == 0) a = cvt8(px + k);
      } else {
        a = cvt8(px + k);
      }
      ac = mfma16(a, ldB<CB>(wxc, wrow + k), ac);
      ah = mfma16(a, ldB<CB>(wxh, wrow + k), ah);
    }
    // phase 2: h_prev part (hi+lo), B cols 1000..1999.  u31: A reads zeroed
    // pad (safe); mask B (w_x* row end).
    {
      bf16x8 a0 = ld8(phh + k), a1 = ld8(phl + k);
      bf16x8 b0, b1;
      if (u == 31) {
        bf16x8 z = {0, 0, 0, 0, 0, 0, 0, 0};
        b0 = z; b1 = z;
        if (quad == 0) { b0 = ldB<CB>(wxc, wrow + 1000 + k);
                         b1 = ldB<CB>(wxh, wrow + 1000 + k); }
      } else {
        b0 = ldB<CB>(wxc, wrow + 1000 + k);
        b1 = ldB<CB>(wxh, wrow + 1000 + k);
      }
      ac = mfma16(a0, b0, ac); ac = mfma16(a1, b0, ac);
      ah = mfma16(a0, b1, ah); ah = mfma16(a1, b1, ah);
    }
  }

  // 16-way split-K reduction: stage 1 all waves write; stage 2 waves 0..7
  // tree-sum one register-slot column each; stage 3 wave 0 epilogue.
  #pragma unroll
  for (int r = 0; r < 4; ++r) {
    red[kc][r][lane]     = ac[r];
    red[kc][4 + r][lane] = ah[r];
  }
  __syncthreads();
  if (kc < 8) {
    float s = red[0][kc][lane];
    #pragma unroll
    for (int x = 1; x < 16; ++x) s += red[x][kc][lane];
    red[0][kc][lane] = s;     // only this thread touches column [*][kc][lane]
  }
  __syncthreads();
  if (kc == 0) {
    #pragma unroll
    for (int r = 0; r < 4; ++r) {
      ac[r] = red[0][r][lane];
      ah[r] = red[0][4 + r][lane];
    }
    const int ne = n0 + l15;
    if (ne < Hh) {
      float bxcv = sanf(bxc[ne]), bxhv = sanf(bxh[ne]);
      #pragma unroll
      for (int r = 0; r < 4; ++r) {
        int me = mc * 16 + quad * 4 + r;
        size_t idx = (size_t)me * HP + ne;
        float c0v = sigm(ac[r] + bxcv);
        float hp = bf2f(hhi[11 * SLOT + idx]) + bf2f(hlo[11 * SLOT + idx]);
        float h0 = sanf(c0v * tanh_(ah[r] + bxhv) + (1.0f - c0v) * hp);
        c0b[idx] = c0v;
        u16 hb = f2bf(h0);
        hhi[idx] = hb;                      // slot 0
        hlo[idx] = f2bf(h0 - bf2f(hb));
      }
    }
  }
}

// ---------------------------------------------------------------------------
// edge level: same 16x16-tile / split-K x16 structure.
// ---------------------------------------------------------------------------
template<bool CB>
__global__ void __launch_bounds__(STPB) edge_kernel(
    int e0, int t, const void* __restrict__ Wh, const void* __restrict__ Wc,
    u16* __restrict__ hhi, u16* __restrict__ hlo,
    const float* __restrict__ c0b, float* __restrict__ outb)
{
  __shared__ float red[16][8][64];      // 32 KB
  const int tid = threadIdx.x;
  const int lane = tid & 63, kc = tid >> 6;
  const int l15 = lane & 15, quad = lane >> 4;
  const int koff = quad * 8;

  const int er = blockIdx.x / MB4;
  const int rem = blockIdx.x - er * MB4;
  const int nt = rem % NTILE, mc = rem / NTILE;
  const int e = e0 + er;
  const int n0 = nt * 16;
  const int we = g_e[e], src = g_src[e], dst = g_dst[e];
  const int nrow = n0 + l15;
  const int ncl = nrow < Hh ? nrow : Hh - 1;
  const size_t wrow = (size_t)we * (Hh * Hh) + (size_t)ncl * Hh;
  const int mrow = mc * 16 + l15;
  const u16* pah = hhi + (size_t)src * SLOT + (size_t)mrow * HP;
  const u16* pal = hlo + (size_t)src * SLOT + (size_t)mrow * HP;

  f32x4 ac = {0.f, 0.f, 0.f, 0.f}, ah = {0.f, 0.f, 0.f, 0.f};
  #pragma unroll
  for (int s = 0; s < 2; ++s) {
    const int u = kc * 2 + s;
    const int k = (u < 31 ? u * 32 : 992) + koff;
    bf16x8 a0 = ld8(pah + k), a1 = ld8(pal + k);
    bf16x8 b0, b1;
    if (u == 31) {     // tail: A reads zeroed pad (safe); mask B (row end)
      bf16x8 z = {0, 0, 0, 0, 0, 0, 0, 0};
      b0 = z; b1 = z;
      if (quad == 0) { b0 = ldB<CB>(Wc, wrow + k); b1 = ldB<CB>(Wh, wrow + k); }
    } else {
      b0 = ldB<CB>(Wc, wrow + k);
      b1 = ldB<CB>(Wh, wrow + k);
    }
    ac = mfma16(a0, b0, ac); ac = mfma16(a1, b0, ac);
    ah = mfma16(a0, b1, ah); ah = mfma16(a1, b1, ah);
  }

  // 16-way split-K reduction
  #pragma unroll
  for (int r = 0; r < 4; ++r) {
    red[kc][r][lane]     = ac[r];
    red[kc][4 + r][lane] = ah[r];
  }
  __syncthreads();
  if (kc < 8) {
    float s = red[0][kc][lane];
    #pragma unroll
    for (int x = 1; x < 16; ++x) s += red[x][kc][lane];
    red[0][kc][lane] = s;
  }
  __syncthreads();
  if (kc == 0) {
    #pragma unroll
    for (int r = 0; r < 4; ++r) {
      ac[r] = red[0][r][lane];
      ah[r] = red[0][4 + r][lane];
    }
    const int ne = n0 + l15;
    if (ne < Hh) {
      const int act = g_act[e], leaf = g_leaf[e];
      const u16* pih = hhi + (size_t)src * SLOT;
      const u16* pil = hlo + (size_t)src * SLOT;
      u16* pjh = hhi + (size_t)dst * SLOT;
      u16* pjl = hlo + (size_t)dst * SLOT;
      #pragma unroll
      for (int r = 0; r < 4; ++r) {
        int me = mc * 16 + quad * 4 + r;
        size_t idx = (size_t)me * HP + ne;
        float cj = sigm(ac[r]);
        float av = actf(act, ah[r]);
        float hi_v = bf2f(pih[idx]) + bf2f(pil[idx]);
        float hj = sanf(cj * av + (1.0f - c0b[idx]) * hi_v);  // blend uses c0 (!)
        u16 hb = f2bf(hj);
        pjh[idx] = hb;
        pjl[idx] = f2bf(hj - bf2f(hb));
        if (leaf) atomicAdd(outb + (size_t)(t * Bb + me) * HP + ne, hj);
      }
    }
  }
}

// fp32 leaf sums (in d_out) -> bf16 * (1/6) into ws.obf; pads stay zero.
__global__ void __launch_bounds__(TPB) cvt_kernel(const float* __restrict__ outb,
                                                  u16* __restrict__ obf) {
  size_t i = ((size_t)blockIdx.x * TPB + threadIdx.x) * 4;
  float4 v = *(const float4*)(outb + i);
  const float s = 1.0f / 6.0f;
  obf[i + 0] = f2bf(sanf(v.x * s));
  obf[i + 1] = f2bf(sanf(v.y * s));
  obf[i + 2] = f2bf(sanf(v.z * s));
  obf[i + 3] = f2bf(sanf(v.w * s));
}

// decoded[4096,10000] = out @ dec_w.T + dec_b, f32 out. 64x64 tile per WG.
__global__ void __launch_bounds__(TPB) decode_kernel(
    const u16* __restrict__ obf, const float* __restrict__ decw,
    const float* __restrict__ decb, float* __restrict__ out)
{
  const int tid = threadIdx.x;
  const int lane = tid & 63, wave = tid >> 6;
  const int l15 = lane & 15, quad = lane >> 4;
  const int bm = blockIdx.x % 64;   // consecutive blocks share bn -> B reuse in L2
  const int bn = blockIdx.x / 64;
  const int mrow = bm * 64 + wave * 16 + l15;
  const u16* pa = obf + (size_t)mrow * HP;
  const float* pb[4];
  #pragma unroll
  for (int j = 0; j < 4; ++j) {
    int v = bn * 64 + j * 16 + l15;
    if (v > Vv - 1) v = Vv - 1;
    pb[j] = decw + (size_t)v * Hh;
  }
  f32x4 acc[4];
  #pragma unroll
  for (int j = 0; j < 4; ++j) acc[j] = (f32x4){0.f, 0.f, 0.f, 0.f};
  const int koff = quad * 8;
  #pragma unroll 2
  for (int c = 0; c < 31; ++c) {
    int k = c * 32 + koff;
    bf16x8 a = ld8(pa + k);
    #pragma unroll
    for (int j = 0; j < 4; ++j) acc[j] = mfma16(a, cvt8(pb[j] + k), acc[j]);
  }
  { // tail: A covers zeroed pads (in-bounds); mask B (dec_w row end)
    int k = 992 + koff;
    bf16x8 a = ld8(pa + k);
    bf16x8 z = {0, 0, 0, 0, 0, 0, 0, 0};
    #pragma unroll
    for (int j = 0; j < 4; ++j) {
      bf16x8 b = z;
      if (quad == 0) b = cvt8(pb[j] + k);
      acc[j] = mfma16(a, b, acc[j]);
    }
  }
  #pragma unroll
  for (int j = 0; j < 4; ++j) {
    int ne = bn * 64 + j * 16 + l15;
    if (ne < Vv) {
      float bv = sanf(decb[ne]);
      #pragma unroll
      for (int r = 0; r < 4; ++r) {
        int me = bm * 64 + wave * 16 + quad * 4 + r;
        out[(size_t)me * Vv + ne] = acc[j][r] + bv;
      }
    }
  }
}

extern "C" void kernel_launch(void* const* d_in, const int* in_sizes, int n_in,
                              void* d_out, int out_size, void* d_ws, size_t ws_size,
                              hipStream_t stream) {
  const int*   inputs = (const int*)d_in[0];
  const float* hidden = (const float*)d_in[1];
  const float* emb    = (const float*)d_in[2];
  const float* wxh    = (const float*)d_in[3];
  const float* bxh    = (const float*)d_in[4];
  const float* wxc    = (const float*)d_in[5];
  const float* bxc    = (const float*)d_in[6];
  const float* Wh     = (const float*)d_in[7];
  const float* Wc     = (const float*)d_in[8];
  const float* decw   = (const float*)d_in[9];
  const float* decb   = (const float*)d_in[10];

  char* ws = (char*)d_ws;
  u16*   hhi = (u16*)(ws);
  u16*   hlo = (u16*)(ws + OFF_HLO);
  float* c0b = (float*)(ws + OFF_C0);
  u16*   obf = (u16*)(ws + OFF_OBF);
  float* outb = (float*)d_out;            // fp32 leaf sums, consumed before decode

  const bool cached = (ws_size >= (size_t)WS_CACHED);
  u16* wxhb = (u16*)(ws + OFF_WC + WC_WXH);
  u16* wxcb = (u16*)(ws + OFF_WC + WC_WXC);
  u16* Whb  = (u16*)(ws + OFF_WC + WC_WH);
  u16* Wcb  = (u16*)(ws + OFF_WC + WC_WCC);

  // zero h hi/lo (pads must be 0) + c0, and the leaf-sum region of d_out
  hipMemsetAsync(ws, 0, OFF_OBF, stream);
  hipMemsetAsync(d_out, 0, OUTB_BYTES, stream);

  if (cached) {
    wcvt_kernel<<<(2000000 / 4 + TPB - 1) / TPB, TPB, 0, stream>>>(wxh, wxhb, 2000000);
    wcvt_kernel<<<(2000000 / 4 + TPB - 1) / TPB, TPB, 0, stream>>>(wxc, wxcb, 2000000);
    wcvt_kernel<<<(11000000 / 4 + TPB - 1) / TPB, TPB, 0, stream>>>(Wh, Whb, 11000000);
    wcvt_kernel<<<(11000000 / 4 + TPB - 1) / TPB, TPB, 0, stream>>>(Wc, Wcb, 11000000);
  }
  stage_kernel<<<Bb, TPB, 0, stream>>>(hidden, hhi, hlo);

  // levels: scheduled positions {0..1},{2..4},{5..6},{7..8},{9..10}
  static const int lev_off[5] = {0, 2, 5, 7, 9};
  static const int lev_cnt[5] = {2, 3, 2, 2, 2};

  for (int t = 0; t < Tt; ++t) {
    if (cached) {
      lev0_kernel<true><<<MB4, STPB, 0, stream>>>(t, inputs, emb, wxhb, bxh,
                                                  wxcb, bxc, hhi, hlo, c0b);
      for (int lev = 0; lev < 5; ++lev)
        edge_kernel<true><<<lev_cnt[lev] * MB4, STPB, 0, stream>>>(
            lev_off[lev], t, Whb, Wcb, hhi, hlo, c0b, outb);
    } else {
      lev0_kernel<false><<<MB4, STPB, 0, stream>>>(t, inputs, emb, wxh, bxh,
                                                   wxc, bxc, hhi, hlo, c0b);
      for (int lev = 0; lev < 5; ++lev)
        edge_kernel<false><<<lev_cnt[lev] * MB4, STPB, 0, stream>>>(
            lev_off[lev], t, Wh, Wc, hhi, hlo, c0b, outb);
    }
  }

  cvt_kernel<<<(Tt * Bb * HP) / (TPB * 4), TPB, 0, stream>>>(outb, obf);
  decode_kernel<<<64 * 157, TPB, 0, stream>>>(obf, decw, decb, (float*)d_out);
}

// Round 10
// 5271.025 us; speedup vs baseline: 1.9298x; 1.0902x over previous
//
#include <hip/hip_runtime.h>

// ============================================================================
// ENAS RNN scan + decode for MI355X (gfx950).  Round 13: r12 scan (proven
// 5747us) + decode with pre-converted bf16 dec_w.
//
// Round-12 post-mortem: WIN (6943->5747).  Scan ~4.7ms (12-14us/level, fixed
// cost ~= work), tail ~1.0ms dominated by decode_kernel, which re-converts
// dec_w f32->bf16 PER BLOCK (64x redundant cvt8 per B tile; ~192 VALU ops vs
// 8 MFMAs per iter -> VALU-bound, 2x B bytes).  Fix: wcvt dec_w once into a
// 20MB bf16 cache in ws (identical f2bf(sanf()) math -> bit-identical
// output); decode ld8's B directly.  Gated on ws_size >= 83.8MB, falls back
// to the old path otherwise.  Scan kernels byte-identical to round 12.
//
// MFMA 16x16x32 bf16 layouts (m89-verified):
//   A: lane holds A[m=lane&15][k=(lane>>4)*8 + j], j=0..7
//   B: lane holds B[k=(lane>>4)*8+j][n=lane&15]
//   C/D: col = lane&15, row = (lane>>4)*4 + reg
// ============================================================================

#define TPB 256            // helper kernels
#define STPB 1024          // scan kernels: 16 waves (= 16 K-chunks)

#define Tt 64
#define Bb 64
#define Hh 1000
#define Ee 1000
#define Vv 10000
#define HP 1024                 // padded row stride for h buffers
#define SLOT (Bb * HP)          // elems per h slot
#define KW 2000                 // E + H (w_x* row length)
#define NTILE 63                // ceil(1000/16)
#define MB4 (NTILE * 4)         // blocks per edge: 63 n-tiles x 4 m-chunks

typedef unsigned short u16;
typedef short bf16x8 __attribute__((ext_vector_type(8)));
typedef float f32x4 __attribute__((ext_vector_type(4)));

// ---- ws layout (bytes) ----
#define OFF_HLO   1572864u     // hhi: 12*SLOT*2
#define OFF_C0    3145728u     // hlo: 12*SLOT*2
#define OFF_OBF   3407872u     // c0 : 64*HP*4
#define OFF_WC    11796480u    // obf: 4096*HP*2 (bf16 outputs for decode A)
#define WC_WXH    0u           // bf16 w_xh  : 2e6*2 = 4,000,000
#define WC_WXC    4000000u     // bf16 w_xc  : 4,000,000
#define WC_WH     8000000u     // bf16 Wh    : 22,000,000
#define WC_WCC    30000000u    // bf16 Wc    : 22,000,000
#define WC_DEC    52000000u    // bf16 dec_w : 1e7*2 = 20,000,000
#define WC_END    52000000u
#define WS_CACHED (OFF_WC + WC_END)             // 63,796,480
#define WS_DEC    (OFF_WC + WC_DEC + 20000000u) // 83,796,480

// outb (fp32 leaf sums, 4096*1024*4 = 16,777,216 B) lives at the start of
// d_out (163.8 MB fp32 output); consumed by cvt before decode writes d_out.
#define OUTB_BYTES 16777216u

__device__ __forceinline__ float bf2f(u16 u) {
  union { unsigned int i; float f; } c; c.i = ((unsigned int)u) << 16; return c.f;
}
__device__ __forceinline__ u16 f2bf(float f) {
  union { float f; unsigned int i; } c; c.f = f;
  unsigned int u = c.i + 0x7FFFu + ((c.i >> 16) & 1u);
  return (u16)(u >> 16);
}
// Sanitize: clamp to +-16, maps NaN -> -16 (fmaxf/fminf return non-NaN arg).
__device__ __forceinline__ float sanf(float x) {
  return fminf(fmaxf(x, -16.0f), 16.0f);
}
__device__ __forceinline__ f32x4 mfma16(bf16x8 a, bf16x8 b, f32x4 c) {
  return __builtin_amdgcn_mfma_f32_16x16x32_bf16(a, b, c, 0, 0, 0);
}
__device__ __forceinline__ bf16x8 ld8(const u16* p) { return *(const bf16x8*)p; }
__device__ __forceinline__ bf16x8 cvt8(const float* p) {
  float4 v0 = *(const float4*)p, v1 = *(const float4*)(p + 4);
  bf16x8 r;
  r[0] = (short)f2bf(sanf(v0.x)); r[1] = (short)f2bf(sanf(v0.y));
  r[2] = (short)f2bf(sanf(v0.z)); r[3] = (short)f2bf(sanf(v0.w));
  r[4] = (short)f2bf(sanf(v1.x)); r[5] = (short)f2bf(sanf(v1.y));
  r[6] = (short)f2bf(sanf(v1.z)); r[7] = (short)f2bf(sanf(v1.w));
  return r;
}
// B-fragment load: cached bf16 (ws) or in-register f32->bf16. Element offset.
template<bool CB>
__device__ __forceinline__ bf16x8 ldB(const void* base, size_t off) {
  if constexpr (CB) return *(const bf16x8*)((const u16*)base + off);
  else              return cvt8((const float*)base + off);
}

__device__ __forceinline__ float sigm(float x) { return 1.0f / (1.0f + __expf(-x)); }
__device__ __forceinline__ float tanh_(float x) {
  float e = __expf(-2.0f * fabsf(x));
  float t = (1.0f - e) / (1.0f + e);
  return x < 0.0f ? -t : t;
}
__device__ __forceinline__ float actf(int a, float x) {
  if (a == 0) return fmaxf(x, 0.0f);   // relu
  if (a == 1) return tanh_(x);         // tanh
  if (a == 2) return sigm(x);          // sigmoid
  return x;                            // identity
}

// Edge schedule, grouped by DAG level (positions 0..10).
// act: 0=relu 1=tanh 2=sigmoid 3=identity
__constant__ short g_e[11]    = {0, 1, 2, 3, 10, 4, 5, 6, 7, 8, 9};
__constant__ short g_src[11]  = {0, 0, 1, 1, 6, 2, 2, 3, 3, 4, 4};
__constant__ short g_dst[11]  = {1, 6, 2, 8, 7, 3, 9, 4, 10, 5, 11};
__constant__ short g_act[11]  = {0, 1, 0, 2, 1, 1, 0, 3, 1, 0, 2};
__constant__ short g_leaf[11] = {0, 0, 0, 1, 1, 0, 1, 0, 1, 1, 1};

// f32 -> sanitized bf16 (weight cache). n divisible by 4.
__global__ void __launch_bounds__(TPB) wcvt_kernel(const float* __restrict__ src,
                                                   u16* __restrict__ dst, int n) {
  int i = (blockIdx.x * TPB + threadIdx.x) * 4;
  if (i < n) {
    float4 v = *(const float4*)(src + i);
    dst[i + 0] = f2bf(sanf(v.x));
    dst[i + 1] = f2bf(sanf(v.y));
    dst[i + 2] = f2bf(sanf(v.z));
    dst[i + 3] = f2bf(sanf(v.w));
  }
}

// hidden [64,1000] f32 -> h slot 11 hi/lo (pads already zeroed by memset).
__global__ void __launch_bounds__(TPB) stage_kernel(const float* __restrict__ hidden,
                                                    u16* __restrict__ hhi,
                                                    u16* __restrict__ hlo) {
  int b = blockIdx.x;
  for (int k = threadIdx.x; k < Hh; k += TPB) {
    float x = sanf(hidden[b * Hh + k]);
    u16 h = f2bf(x);
    hhi[11 * SLOT + b * HP + k] = h;
    hlo[11 * SLOT + b * HP + k] = f2bf(x - bf2f(h));
  }
}

// ---------------------------------------------------------------------------
// lev0: x/h cell.  Block = one 16x16 tile (n-tile nt, m-chunk mc); 16 waves =
// 16 K-chunks; wave kc does K-units {2kc, 2kc+1} of BOTH phases (unit 31 =
// tail).  16-way LDS reduction, epilogue by wave 0.
// ---------------------------------------------------------------------------
template<bool CB>
__global__ void __launch_bounds__(STPB) lev0_kernel(
    int t, const int* __restrict__ inputs, const float* __restrict__ emb,
    const void* __restrict__ wxh, const float* __restrict__ bxh,
    const void* __restrict__ wxc, const float* __restrict__ bxc,
    u16* __restrict__ hhi, u16* __restrict__ hlo, float* __restrict__ c0b)
{
  __shared__ float red[16][8][64];      // 32 KB
  const int tid = threadIdx.x;
  const int lane = tid & 63, kc = tid >> 6;     // wave index = K-chunk
  const int l15 = lane & 15, quad = lane >> 4;
  const int koff = quad * 8;

  const int nt = blockIdx.x % NTILE, mc = blockIdx.x / NTILE;
  const int n0 = nt * 16;
  const int nrow = n0 + l15;
  const int ncl = nrow < Hh ? nrow : Hh - 1;
  const size_t wrow = (size_t)ncl * KW;
  const int mrow = mc * 16 + l15;
  int ix = inputs[t * Bb + mrow];
  ix = ix < 0 ? 0 : (ix >= Vv ? Vv - 1 : ix);   // defensive clamp
  const float* px = emb + (size_t)ix * Ee;
  const u16* phh = hhi + 11 * SLOT + (size_t)mrow * HP;
  const u16* phl = hlo + 11 * SLOT + (size_t)mrow * HP;

  f32x4 ac = {0.f, 0.f, 0.f, 0.f}, ah = {0.f, 0.f, 0.f, 0.f};
  #pragma unroll
  for (int s = 0; s < 2; ++s) {
    const int u = kc * 2 + s;                       // 0..31
    const int k = (u < 31 ? u * 32 : 992) + koff;
    // phase 1: x part (k 0..999).  u31: mask A (emb row end); B in-bounds.
    {
      bf16x8 a;
      if (u == 31) {
        bf16x8 z = {0, 0, 0, 0, 0, 0, 0, 0};
        a = z;
        if (quad == 0) a = cvt8(px + k);
      } else {
        a = cvt8(px + k);
      }
      ac = mfma16(a, ldB<CB>(wxc, wrow + k), ac);
      ah = mfma16(a, ldB<CB>(wxh, wrow + k), ah);
    }
    // phase 2: h_prev part (hi+lo), B cols 1000..1999.  u31: A reads zeroed
    // pad (safe); mask B (w_x* row end).
    {
      bf16x8 a0 = ld8(phh + k), a1 = ld8(phl + k);
      bf16x8 b0, b1;
      if (u == 31) {
        bf16x8 z = {0, 0, 0, 0, 0, 0, 0, 0};
        b0 = z; b1 = z;
        if (quad == 0) { b0 = ldB<CB>(wxc, wrow + 1000 + k);
                         b1 = ldB<CB>(wxh, wrow + 1000 + k); }
      } else {
        b0 = ldB<CB>(wxc, wrow + 1000 + k);
        b1 = ldB<CB>(wxh, wrow + 1000 + k);
      }
      ac = mfma16(a0, b0, ac); ac = mfma16(a1, b0, ac);
      ah = mfma16(a0, b1, ah); ah = mfma16(a1, b1, ah);
    }
  }

  // 16-way split-K reduction: stage 1 all waves write; stage 2 waves 0..7
  // tree-sum one register-slot column each; stage 3 wave 0 epilogue.
  #pragma unroll
  for (int r = 0; r < 4; ++r) {
    red[kc][r][lane]     = ac[r];
    red[kc][4 + r][lane] = ah[r];
  }
  __syncthreads();
  if (kc < 8) {
    float s = red[0][kc][lane];
    #pragma unroll
    for (int x = 1; x < 16; ++x) s += red[x][kc][lane];
    red[0][kc][lane] = s;     // only this thread touches column [*][kc][lane]
  }
  __syncthreads();
  if (kc == 0) {
    #pragma unroll
    for (int r = 0; r < 4; ++r) {
      ac[r] = red[0][r][lane];
      ah[r] = red[0][4 + r][lane];
    }
    const int ne = n0 + l15;
    if (ne < Hh) {
      float bxcv = sanf(bxc[ne]), bxhv = sanf(bxh[ne]);
      #pragma unroll
      for (int r = 0; r < 4; ++r) {
        int me = mc * 16 + quad * 4 + r;
        size_t idx = (size_t)me * HP + ne;
        float c0v = sigm(ac[r] + bxcv);
        float hp = bf2f(hhi[11 * SLOT + idx]) + bf2f(hlo[11 * SLOT + idx]);
        float h0 = sanf(c0v * tanh_(ah[r] + bxhv) + (1.0f - c0v) * hp);
        c0b[idx] = c0v;
        u16 hb = f2bf(h0);
        hhi[idx] = hb;                      // slot 0
        hlo[idx] = f2bf(h0 - bf2f(hb));
      }
    }
  }
}

// ---------------------------------------------------------------------------
// edge level: same 16x16-tile / split-K x16 structure.
// ---------------------------------------------------------------------------
template<bool CB>
__global__ void __launch_bounds__(STPB) edge_kernel(
    int e0, int t, const void* __restrict__ Wh, const void* __restrict__ Wc,
    u16* __restrict__ hhi, u16* __restrict__ hlo,
    const float* __restrict__ c0b, float* __restrict__ outb)
{
  __shared__ float red[16][8][64];      // 32 KB
  const int tid = threadIdx.x;
  const int lane = tid & 63, kc = tid >> 6;
  const int l15 = lane & 15, quad = lane >> 4;
  const int koff = quad * 8;

  const int er = blockIdx.x / MB4;
  const int rem = blockIdx.x - er * MB4;
  const int nt = rem % NTILE, mc = rem / NTILE;
  const int e = e0 + er;
  const int n0 = nt * 16;
  const int we = g_e[e], src = g_src[e], dst = g_dst[e];
  const int nrow = n0 + l15;
  const int ncl = nrow < Hh ? nrow : Hh - 1;
  const size_t wrow = (size_t)we * (Hh * Hh) + (size_t)ncl * Hh;
  const int mrow = mc * 16 + l15;
  const u16* pah = hhi + (size_t)src * SLOT + (size_t)mrow * HP;
  const u16* pal = hlo + (size_t)src * SLOT + (size_t)mrow * HP;

  f32x4 ac = {0.f, 0.f, 0.f, 0.f}, ah = {0.f, 0.f, 0.f, 0.f};
  #pragma unroll
  for (int s = 0; s < 2; ++s) {
    const int u = kc * 2 + s;
    const int k = (u < 31 ? u * 32 : 992) + koff;
    bf16x8 a0 = ld8(pah + k), a1 = ld8(pal + k);
    bf16x8 b0, b1;
    if (u == 31) {     // tail: A reads zeroed pad (safe); mask B (row end)
      bf16x8 z = {0, 0, 0, 0, 0, 0, 0, 0};
      b0 = z; b1 = z;
      if (quad == 0) { b0 = ldB<CB>(Wc, wrow + k); b1 = ldB<CB>(Wh, wrow + k); }
    } else {
      b0 = ldB<CB>(Wc, wrow + k);
      b1 = ldB<CB>(Wh, wrow + k);
    }
    ac = mfma16(a0, b0, ac); ac = mfma16(a1, b0, ac);
    ah = mfma16(a0, b1, ah); ah = mfma16(a1, b1, ah);
  }

  // 16-way split-K reduction
  #pragma unroll
  for (int r = 0; r < 4; ++r) {
    red[kc][r][lane]     = ac[r];
    red[kc][4 + r][lane] = ah[r];
  }
  __syncthreads();
  if (kc < 8) {
    float s = red[0][kc][lane];
    #pragma unroll
    for (int x = 1; x < 16; ++x) s += red[x][kc][lane];
    red[0][kc][lane] = s;
  }
  __syncthreads();
  if (kc == 0) {
    #pragma unroll
    for (int r = 0; r < 4; ++r) {
      ac[r] = red[0][r][lane];
      ah[r] = red[0][4 + r][lane];
    }
    const int ne = n0 + l15;
    if (ne < Hh) {
      const int act = g_act[e], leaf = g_leaf[e];
      const u16* pih = hhi + (size_t)src * SLOT;
      const u16* pil = hlo + (size_t)src * SLOT;
      u16* pjh = hhi + (size_t)dst * SLOT;
      u16* pjl = hlo + (size_t)dst * SLOT;
      #pragma unroll
      for (int r = 0; r < 4; ++r) {
        int me = mc * 16 + quad * 4 + r;
        size_t idx = (size_t)me * HP + ne;
        float cj = sigm(ac[r]);
        float av = actf(act, ah[r]);
        float hi_v = bf2f(pih[idx]) + bf2f(pil[idx]);
        float hj = sanf(cj * av + (1.0f - c0b[idx]) * hi_v);  // blend uses c0 (!)
        u16 hb = f2bf(hj);
        pjh[idx] = hb;
        pjl[idx] = f2bf(hj - bf2f(hb));
        if (leaf) atomicAdd(outb + (size_t)(t * Bb + me) * HP + ne, hj);
      }
    }
  }
}

// fp32 leaf sums (in d_out) -> bf16 * (1/6) into ws.obf; pads stay zero.
__global__ void __launch_bounds__(TPB) cvt_kernel(const float* __restrict__ outb,
                                                  u16* __restrict__ obf) {
  size_t i = ((size_t)blockIdx.x * TPB + threadIdx.x) * 4;
  float4 v = *(const float4*)(outb + i);
  const float s = 1.0f / 6.0f;
  obf[i + 0] = f2bf(sanf(v.x * s));
  obf[i + 1] = f2bf(sanf(v.y * s));
  obf[i + 2] = f2bf(sanf(v.z * s));
  obf[i + 3] = f2bf(sanf(v.w * s));
}

// decoded[4096,10000] = out @ dec_w.T + dec_b, f32 out. 64x64 tile per WG.
// DB: B from pre-converted bf16 cache (ld8) vs f32 cvt8 per use.
template<bool DB>
__global__ void __launch_bounds__(TPB) decode_kernel(
    const u16* __restrict__ obf, const void* __restrict__ bsrc,
    const float* __restrict__ decb, float* __restrict__ out)
{
  const int tid = threadIdx.x;
  const int lane = tid & 63, wave = tid >> 6;
  const int l15 = lane & 15, quad = lane >> 4;
  const int bm = blockIdx.x % 64;   // consecutive blocks share bn -> B reuse in L2
  const int bn = blockIdx.x / 64;
  const int mrow = bm * 64 + wave * 16 + l15;
  const u16* pa = obf + (size_t)mrow * HP;
  size_t boff[4];
  #pragma unroll
  for (int j = 0; j < 4; ++j) {
    int v = bn * 64 + j * 16 + l15;
    if (v > Vv - 1) v = Vv - 1;
    boff[j] = (size_t)v * Hh;
  }
  f32x4 acc[4];
  #pragma unroll
  for (int j = 0; j < 4; ++j) acc[j] = (f32x4){0.f, 0.f, 0.f, 0.f};
  const int koff = quad * 8;
  #pragma unroll 2
  for (int c = 0; c < 31; ++c) {
    int k = c * 32 + koff;
    bf16x8 a = ld8(pa + k);
    #pragma unroll
    for (int j = 0; j < 4; ++j) acc[j] = mfma16(a, ldB<DB>(bsrc, boff[j] + k), acc[j]);
  }
  { // tail: A covers zeroed pads (in-bounds); mask B (dec_w row end)
    int k = 992 + koff;
    bf16x8 a = ld8(pa + k);
    bf16x8 z = {0, 0, 0, 0, 0, 0, 0, 0};
    #pragma unroll
    for (int j = 0; j < 4; ++j) {
      bf16x8 b = z;
      if (quad == 0) b = ldB<DB>(bsrc, boff[j] + k);
      acc[j] = mfma16(a, b, acc[j]);
    }
  }
  #pragma unroll
  for (int j = 0; j < 4; ++j) {
    int ne = bn * 64 + j * 16 + l15;
    if (ne < Vv) {
      float bv = sanf(decb[ne]);
      #pragma unroll
      for (int r = 0; r < 4; ++r) {
        int me = bm * 64 + wave * 16 + quad * 4 + r;
        out[(size_t)me * Vv + ne] = acc[j][r] + bv;
      }
    }
  }
}

extern "C" void kernel_launch(void* const* d_in, const int* in_sizes, int n_in,
                              void* d_out, int out_size, void* d_ws, size_t ws_size,
                              hipStream_t stream) {
  const int*   inputs = (const int*)d_in[0];
  const float* hidden = (const float*)d_in[1];
  const float* emb    = (const float*)d_in[2];
  const float* wxh    = (const float*)d_in[3];
  const float* bxh    = (const float*)d_in[4];
  const float* wxc    = (const float*)d_in[5];
  const float* bxc    = (const float*)d_in[6];
  const float* Wh     = (const float*)d_in[7];
  const float* Wc     = (const float*)d_in[8];
  const float* decw   = (const float*)d_in[9];
  const float* decb   = (const float*)d_in[10];

  char* ws = (char*)d_ws;
  u16*   hhi = (u16*)(ws);
  u16*   hlo = (u16*)(ws + OFF_HLO);
  float* c0b = (float*)(ws + OFF_C0);
  u16*   obf = (u16*)(ws + OFF_OBF);
  float* outb = (float*)d_out;            // fp32 leaf sums, consumed before decode

  const bool cached  = (ws_size >= (size_t)WS_CACHED);
  const bool dcached = (ws_size >= (size_t)WS_DEC);
  u16* wxhb = (u16*)(ws + OFF_WC + WC_WXH);
  u16* wxcb = (u16*)(ws + OFF_WC + WC_WXC);
  u16* Whb  = (u16*)(ws + OFF_WC + WC_WH);
  u16* Wcb  = (u16*)(ws + OFF_WC + WC_WCC);
  u16* dwb  = (u16*)(ws + OFF_WC + WC_DEC);

  // zero h hi/lo (pads must be 0) + c0, and the leaf-sum region of d_out
  hipMemsetAsync(ws, 0, OFF_OBF, stream);
  hipMemsetAsync(d_out, 0, OUTB_BYTES, stream);

  if (cached) {
    wcvt_kernel<<<(2000000 / 4 + TPB - 1) / TPB, TPB, 0, stream>>>(wxh, wxhb, 2000000);
    wcvt_kernel<<<(2000000 / 4 + TPB - 1) / TPB, TPB, 0, stream>>>(wxc, wxcb, 2000000);
    wcvt_kernel<<<(11000000 / 4 + TPB - 1) / TPB, TPB, 0, stream>>>(Wh, Whb, 11000000);
    wcvt_kernel<<<(11000000 / 4 + TPB - 1) / TPB, TPB, 0, stream>>>(Wc, Wcb, 11000000);
  }
  if (dcached) {
    wcvt_kernel<<<(10000000 / 4 + TPB - 1) / TPB, TPB, 0, stream>>>(decw, dwb, 10000000);
  }
  stage_kernel<<<Bb, TPB, 0, stream>>>(hidden, hhi, hlo);

  // levels: scheduled positions {0..1},{2..4},{5..6},{7..8},{9..10}
  static const int lev_off[5] = {0, 2, 5, 7, 9};
  static const int lev_cnt[5] = {2, 3, 2, 2, 2};

  for (int t = 0; t < Tt; ++t) {
    if (cached) {
      lev0_kernel<true><<<MB4, STPB, 0, stream>>>(t, inputs, emb, wxhb, bxh,
                                                  wxcb, bxc, hhi, hlo, c0b);
      for (int lev = 0; lev < 5; ++lev)
        edge_kernel<true><<<lev_cnt[lev] * MB4, STPB, 0, stream>>>(
            lev_off[lev], t, Whb, Wcb, hhi, hlo, c0b, outb);
    } else {
      lev0_kernel<false><<<MB4, STPB, 0, stream>>>(t, inputs, emb, wxh, bxh,
                                                   wxc, bxc, hhi, hlo, c0b);
      for (int lev = 0; lev < 5; ++lev)
        edge_kernel<false><<<lev_cnt[lev] * MB4, STPB, 0, stream>>>(
            lev_off[lev], t, Wh, Wc, hhi, hlo, c0b, outb);
    }
  }

  cvt_kernel<<<(Tt * Bb * HP) / (TPB * 4), TPB, 0, stream>>>(outb, obf);
  if (dcached)
    decode_kernel<true><<<64 * 157, TPB, 0, stream>>>(obf, dwb, decb, (float*)d_out);
  else
    decode_kernel<false><<<64 * 157, TPB, 0, stream>>>(obf, decw, decb, (float*)d_out);
}

// Round 11
// 4458.709 us; speedup vs baseline: 2.2814x; 1.1822x over previous
//
#include <hip/hip_runtime.h>

// ============================================================================
// ENAS RNN scan + decode for MI355X (gfx950).  Round 14: r13 + XCD-grouped
// block swizzle (T1) in the scan kernels.
//
// Round-13 post-mortem: WIN (5747->5271; decode bf16 cache -476us as
// predicted).  Scan ~4.8ms = 12.5us/level remains.  M-split x4 (r12) made
// weight L2 traffic redundant: 4 blocks sharing one weight-row range land on
// up to 4 different XCD L2s, and each XCD's blocks span ~all n-tiles -> each
// XCD re-pulls ~the whole level's weights from LLC, every level.
// Fix: bijective blockIdx remap (m204 formula, W%8-safe) ordering work by
// (nt, er, mc) so bid%8 (XCD) owns a contiguous n-tile range -> per-XCD
// weight footprint drops ~8x.  Pure permutation; math/grids identical.
//
// MFMA 16x16x32 bf16 layouts (m89-verified):
//   A: lane holds A[m=lane&15][k=(lane>>4)*8 + j], j=0..7
//   B: lane holds B[k=(lane>>4)*8+j][n=lane&15]
//   C/D: col = lane&15, row = (lane>>4)*4 + reg
// ============================================================================

#define TPB 256            // helper kernels
#define STPB 1024          // scan kernels: 16 waves (= 16 K-chunks)

#define Tt 64
#define Bb 64
#define Hh 1000
#define Ee 1000
#define Vv 10000
#define HP 1024                 // padded row stride for h buffers
#define SLOT (Bb * HP)          // elems per h slot
#define KW 2000                 // E + H (w_x* row length)
#define NTILE 63                // ceil(1000/16)
#define MB4 (NTILE * 4)         // blocks per edge: 63 n-tiles x 4 m-chunks

typedef unsigned short u16;
typedef short bf16x8 __attribute__((ext_vector_type(8)));
typedef float f32x4 __attribute__((ext_vector_type(4)));

// ---- ws layout (bytes) ----
#define OFF_HLO   1572864u     // hhi: 12*SLOT*2
#define OFF_C0    3145728u     // hlo: 12*SLOT*2
#define OFF_OBF   3407872u     // c0 : 64*HP*4
#define OFF_WC    11796480u    // obf: 4096*HP*2 (bf16 outputs for decode A)
#define WC_WXH    0u           // bf16 w_xh  : 2e6*2 = 4,000,000
#define WC_WXC    4000000u     // bf16 w_xc  : 4,000,000
#define WC_WH     8000000u     // bf16 Wh    : 22,000,000
#define WC_WCC    30000000u    // bf16 Wc    : 22,000,000
#define WC_DEC    52000000u    // bf16 dec_w : 1e7*2 = 20,000,000
#define WC_END    52000000u
#define WS_CACHED (OFF_WC + WC_END)             // 63,796,480
#define WS_DEC    (OFF_WC + WC_DEC + 20000000u) // 83,796,480

// outb (fp32 leaf sums, 4096*1024*4 = 16,777,216 B) lives at the start of
// d_out (163.8 MB fp32 output); consumed by cvt before decode writes d_out.
#define OUTB_BYTES 16777216u

__device__ __forceinline__ float bf2f(u16 u) {
  union { unsigned int i; float f; } c; c.i = ((unsigned int)u) << 16; return c.f;
}
__device__ __forceinline__ u16 f2bf(float f) {
  union { float f; unsigned int i; } c; c.f = f;
  unsigned int u = c.i + 0x7FFFu + ((c.i >> 16) & 1u);
  return (u16)(u >> 16);
}
// Sanitize: clamp to +-16, maps NaN -> -16 (fmaxf/fminf return non-NaN arg).
__device__ __forceinline__ float sanf(float x) {
  return fminf(fmaxf(x, -16.0f), 16.0f);
}
__device__ __forceinline__ f32x4 mfma16(bf16x8 a, bf16x8 b, f32x4 c) {
  return __builtin_amdgcn_mfma_f32_16x16x32_bf16(a, b, c, 0, 0, 0);
}
__device__ __forceinline__ bf16x8 ld8(const u16* p) { return *(const bf16x8*)p; }
__device__ __forceinline__ bf16x8 cvt8(const float* p) {
  float4 v0 = *(const float4*)p, v1 = *(const float4*)(p + 4);
  bf16x8 r;
  r[0] = (short)f2bf(sanf(v0.x)); r[1] = (short)f2bf(sanf(v0.y));
  r[2] = (short)f2bf(sanf(v0.z)); r[3] = (short)f2bf(sanf(v0.w));
  r[4] = (short)f2bf(sanf(v1.x)); r[5] = (short)f2bf(sanf(v1.y));
  r[6] = (short)f2bf(sanf(v1.z)); r[7] = (short)f2bf(sanf(v1.w));
  return r;
}
// B-fragment load: cached bf16 (ws) or in-register f32->bf16. Element offset.
template<bool CB>
__device__ __forceinline__ bf16x8 ldB(const void* base, size_t off) {
  if constexpr (CB) return *(const bf16x8*)((const u16*)base + off);
  else              return cvt8((const float*)base + off);
}

// Bijective XCD-grouping swizzle (m204 formula, valid for any W).  Block i
// (XCD = i%8) gets work item from a contiguous chunk: items ordered by
// (nt, ...) so each XCD owns a contiguous n-tile range of the weights.
__device__ __forceinline__ int xswz(int i, int W) {
  int q = W >> 3, r = W & 7;
  int x = i & 7, j = i >> 3;
  return (x < r ? x * (q + 1) : r * (q + 1) + (x - r) * q) + j;
}

__device__ __forceinline__ float sigm(float x) { return 1.0f / (1.0f + __expf(-x)); }
__device__ __forceinline__ float tanh_(float x) {
  float e = __expf(-2.0f * fabsf(x));
  float t = (1.0f - e) / (1.0f + e);
  return x < 0.0f ? -t : t;
}
__device__ __forceinline__ float actf(int a, float x) {
  if (a == 0) return fmaxf(x, 0.0f);   // relu
  if (a == 1) return tanh_(x);         // tanh
  if (a == 2) return sigm(x);          // sigmoid
  return x;                            // identity
}

// Edge schedule, grouped by DAG level (positions 0..10).
// act: 0=relu 1=tanh 2=sigmoid 3=identity
__constant__ short g_e[11]    = {0, 1, 2, 3, 10, 4, 5, 6, 7, 8, 9};
__constant__ short g_src[11]  = {0, 0, 1, 1, 6, 2, 2, 3, 3, 4, 4};
__constant__ short g_dst[11]  = {1, 6, 2, 8, 7, 3, 9, 4, 10, 5, 11};
__constant__ short g_act[11]  = {0, 1, 0, 2, 1, 1, 0, 3, 1, 0, 2};
__constant__ short g_leaf[11] = {0, 0, 0, 1, 1, 0, 1, 0, 1, 1, 1};

// f32 -> sanitized bf16 (weight cache). n divisible by 4.
__global__ void __launch_bounds__(TPB) wcvt_kernel(const float* __restrict__ src,
                                                   u16* __restrict__ dst, int n) {
  int i = (blockIdx.x * TPB + threadIdx.x) * 4;
  if (i < n) {
    float4 v = *(const float4*)(src + i);
    dst[i + 0] = f2bf(sanf(v.x));
    dst[i + 1] = f2bf(sanf(v.y));
    dst[i + 2] = f2bf(sanf(v.z));
    dst[i + 3] = f2bf(sanf(v.w));
  }
}

// hidden [64,1000] f32 -> h slot 11 hi/lo (pads already zeroed by memset).
__global__ void __launch_bounds__(TPB) stage_kernel(const float* __restrict__ hidden,
                                                    u16* __restrict__ hhi,
                                                    u16* __restrict__ hlo) {
  int b = blockIdx.x;
  for (int k = threadIdx.x; k < Hh; k += TPB) {
    float x = sanf(hidden[b * Hh + k]);
    u16 h = f2bf(x);
    hhi[11 * SLOT + b * HP + k] = h;
    hlo[11 * SLOT + b * HP + k] = f2bf(x - bf2f(h));
  }
}

// ---------------------------------------------------------------------------
// lev0: x/h cell.  Block = one 16x16 tile (n-tile nt, m-chunk mc); 16 waves =
// 16 K-chunks; wave kc does K-units {2kc, 2kc+1} of BOTH phases (unit 31 =
// tail).  16-way LDS reduction, epilogue by wave 0.
// Work item via XCD swizzle: wg ordered by (nt, mc).
// ---------------------------------------------------------------------------
template<bool CB>
__global__ void __launch_bounds__(STPB) lev0_kernel(
    int t, const int* __restrict__ inputs, const float* __restrict__ emb,
    const void* __restrict__ wxh, const float* __restrict__ bxh,
    const void* __restrict__ wxc, const float* __restrict__ bxc,
    u16* __restrict__ hhi, u16* __restrict__ hlo, float* __restrict__ c0b)
{
  __shared__ float red[16][8][64];      // 32 KB
  const int tid = threadIdx.x;
  const int lane = tid & 63, kc = tid >> 6;     // wave index = K-chunk
  const int l15 = lane & 15, quad = lane >> 4;
  const int koff = quad * 8;

  const int wg = xswz(blockIdx.x, MB4);
  const int nt = wg >> 2, mc = wg & 3;
  const int n0 = nt * 16;
  const int nrow = n0 + l15;
  const int ncl = nrow < Hh ? nrow : Hh - 1;
  const size_t wrow = (size_t)ncl * KW;
  const int mrow = mc * 16 + l15;
  int ix = inputs[t * Bb + mrow];
  ix = ix < 0 ? 0 : (ix >= Vv ? Vv - 1 : ix);   // defensive clamp
  const float* px = emb + (size_t)ix * Ee;
  const u16* phh = hhi + 11 * SLOT + (size_t)mrow * HP;
  const u16* phl = hlo + 11 * SLOT + (size_t)mrow * HP;

  f32x4 ac = {0.f, 0.f, 0.f, 0.f}, ah = {0.f, 0.f, 0.f, 0.f};
  #pragma unroll
  for (int s = 0; s < 2; ++s) {
    const int u = kc * 2 + s;                       // 0..31
    const int k = (u < 31 ? u * 32 : 992) + koff;
    // phase 1: x part (k 0..999).  u31: mask A (emb row end); B in-bounds.
    {
      bf16x8 a;
      if (u == 31) {
        bf16x8 z = {0, 0, 0, 0, 0, 0, 0, 0};
        a = z;
        if (quad == 0) a = cvt8(px + k);
      } else {
        a = cvt8(px + k);
      }
      ac = mfma16(a, ldB<CB>(wxc, wrow + k), ac);
      ah = mfma16(a, ldB<CB>(wxh, wrow + k), ah);
    }
    // phase 2: h_prev part (hi+lo), B cols 1000..1999.  u31: A reads zeroed
    // pad (safe); mask B (w_x* row end).
    {
      bf16x8 a0 = ld8(phh + k), a1 = ld8(phl + k);
      bf16x8 b0, b1;
      if (u == 31) {
        bf16x8 z = {0, 0, 0, 0, 0, 0, 0, 0};
        b0 = z; b1 = z;
        if (quad == 0) { b0 = ldB<CB>(wxc, wrow + 1000 + k);
                         b1 = ldB<CB>(wxh, wrow + 1000 + k); }
      } else {
        b0 = ldB<CB>(wxc, wrow + 1000 + k);
        b1 = ldB<CB>(wxh, wrow + 1000 + k);
      }
      ac = mfma16(a0, b0, ac); ac = mfma16(a1, b0, ac);
      ah = mfma16(a0, b1, ah); ah = mfma16(a1, b1, ah);
    }
  }

  // 16-way split-K reduction: stage 1 all waves write; stage 2 waves 0..7
  // tree-sum one register-slot column each; stage 3 wave 0 epilogue.
  #pragma unroll
  for (int r = 0; r < 4; ++r) {
    red[kc][r][lane]     = ac[r];
    red[kc][4 + r][lane] = ah[r];
  }
  __syncthreads();
  if (kc < 8) {
    float s = red[0][kc][lane];
    #pragma unroll
    for (int x = 1; x < 16; ++x) s += red[x][kc][lane];
    red[0][kc][lane] = s;     // only this thread touches column [*][kc][lane]
  }
  __syncthreads();
  if (kc == 0) {
    #pragma unroll
    for (int r = 0; r < 4; ++r) {
      ac[r] = red[0][r][lane];
      ah[r] = red[0][4 + r][lane];
    }
    const int ne = n0 + l15;
    if (ne < Hh) {
      float bxcv = sanf(bxc[ne]), bxhv = sanf(bxh[ne]);
      #pragma unroll
      for (int r = 0; r < 4; ++r) {
        int me = mc * 16 + quad * 4 + r;
        size_t idx = (size_t)me * HP + ne;
        float c0v = sigm(ac[r] + bxcv);
        float hp = bf2f(hhi[11 * SLOT + idx]) + bf2f(hlo[11 * SLOT + idx]);
        float h0 = sanf(c0v * tanh_(ah[r] + bxhv) + (1.0f - c0v) * hp);
        c0b[idx] = c0v;
        u16 hb = f2bf(h0);
        hhi[idx] = hb;                      // slot 0
        hlo[idx] = f2bf(h0 - bf2f(hb));
      }
    }
  }
}

// ---------------------------------------------------------------------------
// edge level: same 16x16-tile / split-K x16 structure.
// Work item via XCD swizzle: wg ordered by (nt, er, mc) -> each XCD owns a
// contiguous n-tile (weight-row) range across the level's edges.
// ---------------------------------------------------------------------------
template<bool CB>
__global__ void __launch_bounds__(STPB) edge_kernel(
    int e0, int t, const void* __restrict__ Wh, const void* __restrict__ Wc,
    u16* __restrict__ hhi, u16* __restrict__ hlo,
    const float* __restrict__ c0b, float* __restrict__ outb)
{
  __shared__ float red[16][8][64];      // 32 KB
  const int tid = threadIdx.x;
  const int lane = tid & 63, kc = tid >> 6;
  const int l15 = lane & 15, quad = lane >> 4;
  const int koff = quad * 8;

  const int wg = xswz(blockIdx.x, gridDim.x);
  const int cnt4 = gridDim.x / NTILE;           // cnt * 4
  const int nt = wg / cnt4;
  const int rem = wg - nt * cnt4;
  const int er = rem >> 2, mc = rem & 3;
  const int e = e0 + er;
  const int n0 = nt * 16;
  const int we = g_e[e], src = g_src[e], dst = g_dst[e];
  const int nrow = n0 + l15;
  const int ncl = nrow < Hh ? nrow : Hh - 1;
  const size_t wrow = (size_t)we * (Hh * Hh) + (size_t)ncl * Hh;
  const int mrow = mc * 16 + l15;
  const u16* pah = hhi + (size_t)src * SLOT + (size_t)mrow * HP;
  const u16* pal = hlo + (size_t)src * SLOT + (size_t)mrow * HP;

  f32x4 ac = {0.f, 0.f, 0.f, 0.f}, ah = {0.f, 0.f, 0.f, 0.f};
  #pragma unroll
  for (int s = 0; s < 2; ++s) {
    const int u = kc * 2 + s;
    const int k = (u < 31 ? u * 32 : 992) + koff;
    bf16x8 a0 = ld8(pah + k), a1 = ld8(pal + k);
    bf16x8 b0, b1;
    if (u == 31) {     // tail: A reads zeroed pad (safe); mask B (row end)
      bf16x8 z = {0, 0, 0, 0, 0, 0, 0, 0};
      b0 = z; b1 = z;
      if (quad == 0) { b0 = ldB<CB>(Wc, wrow + k); b1 = ldB<CB>(Wh, wrow + k); }
    } else {
      b0 = ldB<CB>(Wc, wrow + k);
      b1 = ldB<CB>(Wh, wrow + k);
    }
    ac = mfma16(a0, b0, ac); ac = mfma16(a1, b0, ac);
    ah = mfma16(a0, b1, ah); ah = mfma16(a1, b1, ah);
  }

  // 16-way split-K reduction
  #pragma unroll
  for (int r = 0; r < 4; ++r) {
    red[kc][r][lane]     = ac[r];
    red[kc][4 + r][lane] = ah[r];
  }
  __syncthreads();
  if (kc < 8) {
    float s = red[0][kc][lane];
    #pragma unroll
    for (int x = 1; x < 16; ++x) s += red[x][kc][lane];
    red[0][kc][lane] = s;
  }
  __syncthreads();
  if (kc == 0) {
    #pragma unroll
    for (int r = 0; r < 4; ++r) {
      ac[r] = red[0][r][lane];
      ah[r] = red[0][4 + r][lane];
    }
    const int ne = n0 + l15;
    if (ne < Hh) {
      const int act = g_act[e], leaf = g_leaf[e];
      const u16* pih = hhi + (size_t)src * SLOT;
      const u16* pil = hlo + (size_t)src * SLOT;
      u16* pjh = hhi + (size_t)dst * SLOT;
      u16* pjl = hlo + (size_t)dst * SLOT;
      #pragma unroll
      for (int r = 0; r < 4; ++r) {
        int me = mc * 16 + quad * 4 + r;
        size_t idx = (size_t)me * HP + ne;
        float cj = sigm(ac[r]);
        float av = actf(act, ah[r]);
        float hi_v = bf2f(pih[idx]) + bf2f(pil[idx]);
        float hj = sanf(cj * av + (1.0f - c0b[idx]) * hi_v);  // blend uses c0 (!)
        u16 hb = f2bf(hj);
        pjh[idx] = hb;
        pjl[idx] = f2bf(hj - bf2f(hb));
        if (leaf) atomicAdd(outb + (size_t)(t * Bb + me) * HP + ne, hj);
      }
    }
  }
}

// fp32 leaf sums (in d_out) -> bf16 * (1/6) into ws.obf; pads stay zero.
__global__ void __launch_bounds__(TPB) cvt_kernel(const float* __restrict__ outb,
                                                  u16* __restrict__ obf) {
  size_t i = ((size_t)blockIdx.x * TPB + threadIdx.x) * 4;
  float4 v = *(const float4*)(outb + i);
  const float s = 1.0f / 6.0f;
  obf[i + 0] = f2bf(sanf(v.x * s));
  obf[i + 1] = f2bf(sanf(v.y * s));
  obf[i + 2] = f2bf(sanf(v.z * s));
  obf[i + 3] = f2bf(sanf(v.w * s));
}

// decoded[4096,10000] = out @ dec_w.T + dec_b, f32 out. 64x64 tile per WG.
// DB: B from pre-converted bf16 cache (ld8) vs f32 cvt8 per use.
template<bool DB>
__global__ void __launch_bounds__(TPB) decode_kernel(
    const u16* __restrict__ obf, const void* __restrict__ bsrc,
    const float* __restrict__ decb, float* __restrict__ out)
{
  const int tid = threadIdx.x;
  const int lane = tid & 63, wave = tid >> 6;
  const int l15 = lane & 15, quad = lane >> 4;
  const int bm = blockIdx.x % 64;   // consecutive blocks share bn -> B reuse in L2
  const int bn = blockIdx.x / 64;
  const int mrow = bm * 64 + wave * 16 + l15;
  const u16* pa = obf + (size_t)mrow * HP;
  size_t boff[4];
  #pragma unroll
  for (int j = 0; j < 4; ++j) {
    int v = bn * 64 + j * 16 + l15;
    if (v > Vv - 1) v = Vv - 1;
    boff[j] = (size_t)v * Hh;
  }
  f32x4 acc[4];
  #pragma unroll
  for (int j = 0; j < 4; ++j) acc[j] = (f32x4){0.f, 0.f, 0.f, 0.f};
  const int koff = quad * 8;
  #pragma unroll 2
  for (int c = 0; c < 31; ++c) {
    int k = c * 32 + koff;
    bf16x8 a = ld8(pa + k);
    #pragma unroll
    for (int j = 0; j < 4; ++j) acc[j] = mfma16(a, ldB<DB>(bsrc, boff[j] + k), acc[j]);
  }
  { // tail: A covers zeroed pads (in-bounds); mask B (dec_w row end)
    int k = 992 + koff;
    bf16x8 a = ld8(pa + k);
    bf16x8 z = {0, 0, 0, 0, 0, 0, 0, 0};
    #pragma unroll
    for (int j = 0; j < 4; ++j) {
      bf16x8 b = z;
      if (quad == 0) b = ldB<DB>(bsrc, boff[j] + k);
      acc[j] = mfma16(a, b, acc[j]);
    }
  }
  #pragma unroll
  for (int j = 0; j < 4; ++j) {
    int ne = bn * 64 + j * 16 + l15;
    if (ne < Vv) {
      float bv = sanf(decb[ne]);
      #pragma unroll
      for (int r = 0; r < 4; ++r) {
        int me = bm * 64 + wave * 16 + quad * 4 + r;
        out[(size_t)me * Vv + ne] = acc[j][r] + bv;
      }
    }
  }
}

extern "C" void kernel_launch(void* const* d_in, const int* in_sizes, int n_in,
                              void* d_out, int out_size, void* d_ws, size_t ws_size,
                              hipStream_t stream) {
  const int*   inputs = (const int*)d_in[0];
  const float* hidden = (const float*)d_in[1];
  const float* emb    = (const float*)d_in[2];
  const float* wxh    = (const float*)d_in[3];
  const float* bxh    = (const float*)d_in[4];
  const float* wxc    = (const float*)d_in[5];
  const float* bxc    = (const float*)d_in[6];
  const float* Wh     = (const float*)d_in[7];
  const float* Wc     = (const float*)d_in[8];
  const float* decw   = (const float*)d_in[9];
  const float* decb   = (const float*)d_in[10];

  char* ws = (char*)d_ws;
  u16*   hhi = (u16*)(ws);
  u16*   hlo = (u16*)(ws + OFF_HLO);
  float* c0b = (float*)(ws + OFF_C0);
  u16*   obf = (u16*)(ws + OFF_OBF);
  float* outb = (float*)d_out;            // fp32 leaf sums, consumed before decode

  const bool cached  = (ws_size >= (size_t)WS_CACHED);
  const bool dcached = (ws_size >= (size_t)WS_DEC);
  u16* wxhb = (u16*)(ws + OFF_WC + WC_WXH);
  u16* wxcb = (u16*)(ws + OFF_WC + WC_WXC);
  u16* Whb  = (u16*)(ws + OFF_WC + WC_WH);
  u16* Wcb  = (u16*)(ws + OFF_WC + WC_WCC);
  u16* dwb  = (u16*)(ws + OFF_WC + WC_DEC);

  // zero h hi/lo (pads must be 0) + c0, and the leaf-sum region of d_out
  hipMemsetAsync(ws, 0, OFF_OBF, stream);
  hipMemsetAsync(d_out, 0, OUTB_BYTES, stream);

  if (cached) {
    wcvt_kernel<<<(2000000 / 4 + TPB - 1) / TPB, TPB, 0, stream>>>(wxh, wxhb, 2000000);
    wcvt_kernel<<<(2000000 / 4 + TPB - 1) / TPB, TPB, 0, stream>>>(wxc, wxcb, 2000000);
    wcvt_kernel<<<(11000000 / 4 + TPB - 1) / TPB, TPB, 0, stream>>>(Wh, Whb, 11000000);
    wcvt_kernel<<<(11000000 / 4 + TPB - 1) / TPB, TPB, 0, stream>>>(Wc, Wcb, 11000000);
  }
  if (dcached) {
    wcvt_kernel<<<(10000000 / 4 + TPB - 1) / TPB, TPB, 0, stream>>>(decw, dwb, 10000000);
  }
  stage_kernel<<<Bb, TPB, 0, stream>>>(hidden, hhi, hlo);

  // levels: scheduled positions {0..1},{2..4},{5..6},{7..8},{9..10}
  static const int lev_off[5] = {0, 2, 5, 7, 9};
  static const int lev_cnt[5] = {2, 3, 2, 2, 2};

  for (int t = 0; t < Tt; ++t) {
    if (cached) {
      lev0_kernel<true><<<MB4, STPB, 0, stream>>>(t, inputs, emb, wxhb, bxh,
                                                  wxcb, bxc, hhi, hlo, c0b);
      for (int lev = 0; lev < 5; ++lev)
        edge_kernel<true><<<lev_cnt[lev] * MB4, STPB, 0, stream>>>(
            lev_off[lev], t, Whb, Wcb, hhi, hlo, c0b, outb);
    } else {
      lev0_kernel<false><<<MB4, STPB, 0, stream>>>(t, inputs, emb, wxh, bxh,
                                                   wxc, bxc, hhi, hlo, c0b);
      for (int lev = 0; lev < 5; ++lev)
        edge_kernel<false><<<lev_cnt[lev] * MB4, STPB, 0, stream>>>(
            lev_off[lev], t, Wh, Wc, hhi, hlo, c0b, outb);
    }
  }

  cvt_kernel<<<(Tt * Bb * HP) / (TPB * 4), TPB, 0, stream>>>(outb, obf);
  if (dcached)
    decode_kernel<true><<<64 * 157, TPB, 0, stream>>>(obf, dwb, decb, (float*)d_out);
  else
    decode_kernel<false><<<64 * 157, TPB, 0, stream>>>(obf, decw, decb, (float*)d_out);
}